// Round 1
// baseline (1208.288 us; speedup 1.0000x reference)
//
#include <hip/hip_runtime.h>
#include <hip/hip_bf16.h>
#include <math.h>

typedef __bf16 bf16;
typedef __bf16 v8bf __attribute__((ext_vector_type(8)));
typedef float v4f __attribute__((ext_vector_type(4)));

#define B_   4
#define S_   2048
#define E_   1024
#define CS_  16
#define NC_  8
#define H_   16
#define D_   1040
#define DH_  65
#define DFF_ 4096
#define M_   8192
#define KC_  1056          // padded per-c chunk
#define KH_  (4 * KC_)     // 4224, half-K
#define KB2_ (8 * KC_)     // 8448, B' row length

__device__ __forceinline__ v4f mfma16(v8bf a, v8bf b, v4f c) {
    return __builtin_amdgcn_mfma_f32_16x16x32_bf16(a, b, c, 0, 0, 0);
}

__device__ __forceinline__ void async16(const bf16* g, bf16* l) {
    __builtin_amdgcn_global_load_lds(
        (const __attribute__((address_space(1))) unsigned int*)g,
        (__attribute__((address_space(3))) unsigned int*)l, 16, 0, 0);
}

// ---------------- f32 -> bf16 weight conversion ----------------
__global__ __launch_bounds__(256) void k_cvt(const float* __restrict__ src,
                                             bf16* __restrict__ dst, int n) {
    int i = (blockIdx.x * 256 + threadIdx.x) * 4;
    if (i + 4 <= n) {
        float4 v = *(const float4*)(src + i);
        bf16 o[4] = {(bf16)v.x, (bf16)v.y, (bf16)v.z, (bf16)v.w};
        *(ushort4*)(dst + i) = *(const ushort4*)o;
    }
}

// ---------------- build B' for K-projection: Wk[c][n][j] -> B'[n][c*1056+j] ----------------
__global__ __launch_bounds__(256) void k_build_bk(const float* __restrict__ Wk,
                                                  bf16* __restrict__ Bp) {
    int c = blockIdx.y;
    int idx = blockIdx.x * 256 + threadIdx.x;     // 1040 * 130
    if (idx >= 1040 * 130) return;
    int n = idx / 130, u = idx - n * 130;
    const float* src = Wk + ((size_t)(c * D_ + n)) * D_ + u * 8;
    float4 a = *(const float4*)src;
    float4 b = *(const float4*)(src + 4);
    bf16 o[8] = {(bf16)a.x, (bf16)a.y, (bf16)a.z, (bf16)a.w,
                 (bf16)b.x, (bf16)b.y, (bf16)b.z, (bf16)b.w};
    *(uint4*)(Bp + (size_t)n * KB2_ + c * KC_ + u * 8) = *(const uint4*)o;
}

// ---------------- build half A': A'[m][cc*1056+j] = w[m,coff+cc]*xc[m][j] ----------------
__global__ __launch_bounds__(256) void k_scale_a(const bf16* __restrict__ xc,
                                                 const float* __restrict__ cond,
                                                 int coff, bf16* __restrict__ Ap) {
    int idx = blockIdx.x * 256 + threadIdx.x;     // 8192 * 132
    int m = idx / 132, u = idx - m * 132;
    int j = u * 8;
    float4 w4 = *(const float4*)(cond + (size_t)m * CS_ + coff);
    float wv[4] = {w4.x, w4.y, w4.z, w4.w};
    bf16* dst = Ap + (size_t)m * KH_ + j;
    if (j < D_) {
        union { uint4 u4; bf16 h[8]; } src;
        src.u4 = *(const uint4*)(xc + (size_t)m * D_ + j);
        float xv[8];
#pragma unroll
        for (int e = 0; e < 8; ++e) xv[e] = (float)src.h[e];
#pragma unroll
        for (int cc = 0; cc < 4; ++cc) {
            bf16 o[8];
#pragma unroll
            for (int e = 0; e < 8; ++e) o[e] = (bf16)(xv[e] * wv[cc]);
            *(uint4*)(dst + cc * KC_) = *(const uint4*)o;
        }
    } else {
        uint4 z = {0u, 0u, 0u, 0u};
#pragma unroll
        for (int cc = 0; cc < 4; ++cc) *(uint4*)(dst + cc * KC_) = z;
    }
}

// ---------------- zero qp/kp pad columns (d in [64,96) per row) ----------------
__global__ __launch_bounds__(256) void k_zero_pads(bf16* __restrict__ qp,
                                                   bf16* __restrict__ kp) {
    int i = blockIdx.x * 256 + threadIdx.x;     // 131072 rows * 8 uint4
    int row = i >> 3, j = i & 7;
    uint4 z = {0u, 0u, 0u, 0u};
    bf16* base = (j < 4) ? qp : kp;
    ((uint4*)(base + (size_t)row * 96 + 64))[j & 3] = z;
}

// ---------------- LayerNorm(x f32) + concat cond -> xc (M x D) bf16 ----------------
__global__ __launch_bounds__(256) void k_ln_concat(
    const float* __restrict__ x, const float* __restrict__ cond,
    const float* __restrict__ g, const float* __restrict__ bn,
    bf16* __restrict__ xc)
{
    int row = blockIdx.x;
    int t = threadIdx.x;
    const float* xr = x + (size_t)row * E_;
    float4 v = *(const float4*)(xr + t * 4);
    float s = v.x + v.y + v.z + v.w;
    float ss = v.x * v.x + v.y * v.y + v.z * v.z + v.w * v.w;
#pragma unroll
    for (int off = 32; off; off >>= 1) {
        s  += __shfl_down(s, off);
        ss += __shfl_down(ss, off);
    }
    __shared__ float red[8];
    int wid = t >> 6;
    if ((t & 63) == 0) { red[wid] = s; red[4 + wid] = ss; }
    __syncthreads();
    float stot  = red[0] + red[1] + red[2] + red[3];
    float sstot = red[4] + red[5] + red[6] + red[7];
    float mean = stot * (1.0f / E_);
    float var  = sstot * (1.0f / E_) - mean * mean;
    float rs = rsqrtf(var + 1e-5f);
    bf16* xcr = xc + (size_t)row * D_;
    float vv[4] = {v.x, v.y, v.z, v.w};
#pragma unroll
    for (int j = 0; j < 4; ++j) {
        int i = t * 4 + j;
        xcr[i] = (bf16)(((vv[j] - mean) * rs) * g[i] + bn[i]);
    }
    if (t < CS_) xcr[E_ + t] = (bf16)cond[(size_t)row * CS_ + t];
}

// ---------------- K-projection GEMM half: pure async16, K=4224, no remainder ----------------
__global__ __launch_bounds__(256) void k_gemm_k2(
    const bf16* __restrict__ A, const bf16* __restrict__ Bm,
    int koffB, bf16* __restrict__ Pout)
{
    __shared__ bf16 As[128][32];
    __shared__ bf16 Bs[128][32];
    int t = threadIdx.x;

    int pid = blockIdx.x;             // 576 = 8 gid * (8 mi * 9 ni)
    int gid = pid / 72;
    int rem = pid - gid * 72;
    int mi = gid * 8 + (rem & 7);
    int ni = rem >> 3;
    int m0 = mi << 7, n0 = ni << 7;

    int lane = t & 63, w = t >> 6;
    int wm = (w >> 1) * 64, wn = (w & 1) * 64;
    int lr = lane & 15, lq = lane >> 4;

    int row_i[2], seg_i[2];
#pragma unroll
    for (int i = 0; i < 2; ++i) { row_i[i] = (t + i * 256) >> 2; seg_i[i] = (t + i * 256) & 3; }

    v4f acc[4][4];
    v4f vzero = {0.f, 0.f, 0.f, 0.f};
#pragma unroll
    for (int mt = 0; mt < 4; ++mt)
#pragma unroll
        for (int nt = 0; nt < 4; ++nt) acc[mt][nt] = vzero;

    for (int kb = 0; kb < KH_ / 32; ++kb) {
        int k0 = kb << 5;
#pragma unroll
        for (int i = 0; i < 2; ++i) {
            async16(A + (size_t)(m0 + row_i[i]) * KH_ + k0 + seg_i[i] * 8,
                    &As[0][0] + (t + i * 256) * 8);
            async16(Bm + (size_t)(n0 + row_i[i]) * KB2_ + koffB + k0 + seg_i[i] * 8,
                    &Bs[0][0] + (t + i * 256) * 8);
        }
        __syncthreads();
        v8bf af[4], bfr[4];
#pragma unroll
        for (int mt = 0; mt < 4; ++mt) af[mt]  = *(const v8bf*)(&As[wm + mt * 16 + lr][lq * 8]);
#pragma unroll
        for (int nt = 0; nt < 4; ++nt) bfr[nt] = *(const v8bf*)(&Bs[wn + nt * 16 + lr][lq * 8]);
#pragma unroll
        for (int mt = 0; mt < 4; ++mt)
#pragma unroll
            for (int nt = 0; nt < 4; ++nt)
                acc[mt][nt] = mfma16(af[mt], bfr[nt], acc[mt][nt]);
        __syncthreads();
    }

#pragma unroll
    for (int mt = 0; mt < 4; ++mt)
#pragma unroll
        for (int reg = 0; reg < 4; ++reg) {
            int grow = m0 + wm + mt * 16 + lq * 4 + reg;
#pragma unroll
            for (int nt = 0; nt < 4; ++nt) {
                int gcol = n0 + wn + nt * 16 + lr;
                if (gcol < D_)
                    Pout[(size_t)grow * D_ + gcol] = (bf16)acc[mt][nt][reg];
            }
        }
}

// ---------------- combine K partials + cond*bk bias -> kp padded layout ----------------
__global__ __launch_bounds__(256) void k_comb_k(
    const bf16* __restrict__ P0, const bf16* __restrict__ P1,
    const float* __restrict__ condw, const float* __restrict__ bkp,
    bf16* __restrict__ kp)
{
    int idx = blockIdx.x * 256 + threadIdx.x;   // 8192*1040
    int m = idx / 1040, n = idx - m * 1040;
    float v = (float)P0[idx] + (float)P1[idx];
#pragma unroll
    for (int c = 0; c < NC_; ++c)
        v += condw[(size_t)m * CS_ + c] * bkp[(size_t)c * D_ + n];
    int h = n / 65, d = n - h * 65;
    int b = m >> 11, s = m & 2047;
    kp[(((size_t)(b * 16 + h)) * S_ + s) * 96 + d] = (bf16)v;
}

// ---------------- generic GEMM w/ epilogues (QV, O, FF1, FF2) ----------------
#define EP_QV  0
#define EP_O   1
#define EP_FF1 2
#define EP_FF2 3

template<int EP>
__global__ __launch_bounds__(256) void k_gemm(
    const bf16* __restrict__ A, const bf16* __restrict__ Bm,
    const float* __restrict__ bias, const float* __restrict__ bias2,
    int M, int N, int K, int lda, int ldb, int nbn,
    bf16* __restrict__ Cb, float* __restrict__ Cf, int ldc,
    const bf16* __restrict__ res, int ldres, bf16* __restrict__ Cb2)
{
    __shared__ bf16 As[128][32];
    __shared__ bf16 Bs[128][32];
    int t = threadIdx.x;

    int pid = blockIdx.x;
    int nig = 8 * nbn;
    int gid = pid / nig;
    int rem = pid - gid * nig;
    int mi = gid * 8 + (rem & 7);
    int ni = rem >> 3;
    int m0 = mi << 7, n0 = ni << 7;

    int lane = t & 63, w = t >> 6;
    int wm = (w >> 1) * 64, wn = (w & 1) * 64;
    int lr = lane & 15, lq = lane >> 4;

    int row_i[2], seg_i[2];
#pragma unroll
    for (int i = 0; i < 2; ++i) { row_i[i] = (t + i * 256) >> 2; seg_i[i] = (t + i * 256) & 3; }

    v4f acc[4][4];
    v4f vzero = {0.f, 0.f, 0.f, 0.f};
#pragma unroll
    for (int mt = 0; mt < 4; ++mt)
#pragma unroll
        for (int nt = 0; nt < 4; ++nt) acc[mt][nt] = vzero;

    const int KF = K >> 5;
    const bool KR = (K & 31) != 0;

    for (int kb = 0; kb < KF; ++kb) {
        int k0 = kb << 5;
#pragma unroll
        for (int i = 0; i < 2; ++i) {
            async16(A + (size_t)(m0 + row_i[i]) * lda + k0 + seg_i[i] * 8,
                    &As[0][0] + (t + i * 256) * 8);
            async16(Bm + (size_t)(n0 + row_i[i]) * ldb + k0 + seg_i[i] * 8,
                    &Bs[0][0] + (t + i * 256) * 8);
        }
        __syncthreads();
        v8bf af[4], bfr[4];
#pragma unroll
        for (int mt = 0; mt < 4; ++mt) af[mt]  = *(const v8bf*)(&As[wm + mt * 16 + lr][lq * 8]);
#pragma unroll
        for (int nt = 0; nt < 4; ++nt) bfr[nt] = *(const v8bf*)(&Bs[wn + nt * 16 + lr][lq * 8]);
#pragma unroll
        for (int mt = 0; mt < 4; ++mt)
#pragma unroll
            for (int nt = 0; nt < 4; ++nt)
                acc[mt][nt] = mfma16(af[mt], bfr[nt], acc[mt][nt]);
        __syncthreads();
    }
    if (KR) {
        int k0 = KF << 5;
#pragma unroll
        for (int i = 0; i < 2; ++i) {
            int gk = k0 + seg_i[i] * 8;
            uint4 val = {0u, 0u, 0u, 0u};
            if (gk + 8 <= K) val = *(const uint4*)(A + (size_t)(m0 + row_i[i]) * lda + gk);
            *(uint4*)(&As[row_i[i]][seg_i[i] * 8]) = val;
            uint4 bv = {0u, 0u, 0u, 0u};
            int gn = n0 + row_i[i];
            if (gn < N && gk + 8 <= K) bv = *(const uint4*)(Bm + (size_t)gn * ldb + gk);
            *(uint4*)(&Bs[row_i[i]][seg_i[i] * 8]) = bv;
        }
        __syncthreads();
        v8bf af[4], bfr[4];
#pragma unroll
        for (int mt = 0; mt < 4; ++mt) af[mt]  = *(const v8bf*)(&As[wm + mt * 16 + lr][lq * 8]);
#pragma unroll
        for (int nt = 0; nt < 4; ++nt) bfr[nt] = *(const v8bf*)(&Bs[wn + nt * 16 + lr][lq * 8]);
#pragma unroll
        for (int mt = 0; mt < 4; ++mt)
#pragma unroll
            for (int nt = 0; nt < 4; ++nt)
                acc[mt][nt] = mfma16(af[mt], bfr[nt], acc[mt][nt]);
        __syncthreads();
    }

#pragma unroll
    for (int mt = 0; mt < 4; ++mt) {
#pragma unroll
        for (int reg = 0; reg < 4; ++reg) {
            int grow = m0 + wm + mt * 16 + lq * 4 + reg;
#pragma unroll
            for (int nt = 0; nt < 4; ++nt) {
                int gcol = n0 + wn + nt * 16 + lr;
                float vacc = acc[mt][nt][reg];
                if constexpr (EP == EP_QV) {
                    if (gcol < D_) { // Q -> qp padded layout, pre-scaled by log2e/sqrt(65)
                        float o = (vacc + bias[gcol]) * 0.1789442960f;
                        int h = gcol / 65, d = gcol - h * 65;
                        int b = grow >> 11, s = grow & 2047;
                        Cb[(((size_t)(b * 16 + h)) * S_ + s) * 96 + d] = (bf16)o;
                    } else if (gcol < 2 * D_) { // V -> vb row-major
                        int col = gcol - D_;
                        Cb2[(size_t)grow * D_ + col] = (bf16)(vacc + bias2[col]);
                    }
                } else if constexpr (EP == EP_O) {
                    float o = vacc + bias[gcol] + (float)res[(size_t)grow * ldres + gcol];
                    Cb[(size_t)grow * ldc + gcol] = (bf16)o;
                } else if constexpr (EP == EP_FF1) {
                    float o = vacc + bias[gcol];
                    Cb[(size_t)grow * ldc + gcol] = (bf16)fmaxf(o, 0.f);
                } else { // EP_FF2 -> f32 z with bias + residual
                    Cf[(size_t)grow * ldc + gcol] =
                        vacc + bias[gcol] + (float)res[(size_t)grow * ldres + gcol];
                }
            }
        }
    }
}

// ---------------- transpose v (M x D bf16) into vt [bh][d(80)][s] ----------------
__global__ __launch_bounds__(256) void k_transpose_v(
    const bf16* __restrict__ v, bf16* __restrict__ vt)
{
    int bh = blockIdx.y, s0 = blockIdx.x * 64;
    int b = bh >> 4, h = bh & 15;
    __shared__ bf16 tile[80][65];
#pragma unroll
    for (int i = 0; i < 20; ++i) {
        int idx = threadIdx.x + i * 256;
        int d = idx % 80, sl = idx / 80;
        bf16 val = (bf16)0.f;
        if (d < DH_) val = v[((size_t)b * S_ + s0 + sl) * D_ + h * DH_ + d];
        tile[d][sl] = val;
    }
    __syncthreads();
#pragma unroll
    for (int i = 0; i < 20; ++i) {
        int idx = threadIdx.x + i * 256;
        int sl = idx % 64, d = idx / 64;
        vt[((size_t)bh * 80 + d) * S_ + s0 + sl] = tile[d][sl];
    }
}

// ---------------- flash attention (S^T layout, lane-local softmax, reg prefetch) ----------------
__global__ __launch_bounds__(256, 4) void k_attn(
    const bf16* __restrict__ qp, const bf16* __restrict__ kp,
    const bf16* __restrict__ vt, bf16* __restrict__ o)
{
    int bh = blockIdx.y;
    int s0 = blockIdx.x * 64;
    int b = bh >> 4, h = bh & 15;
    int t = threadIdx.x, lane = t & 63, w = t >> 6;
    int lr = lane & 15, lq = lane >> 4;

    __shared__ bf16 Ks[64][104];
    __shared__ bf16 Vs[80][72];
    __shared__ bf16 Psh[4][16 * 72];
    bf16* Ps = Psh[w];

    // Q fragments straight from global: row (w*16+lr), 16B-aligned chunks
    const bf16* qbase = qp + ((size_t)bh * S_ + s0 + w * 16 + lr) * 96;
    v8bf qreg[3];
#pragma unroll
    for (int ks = 0; ks < 3; ++ks)
        qreg[ks] = *(const v8bf*)(qbase + ks * 32 + lq * 8);

    // staging index sets (K: 768 uint4, V: 640 uint4)
    int kro[3], kso[3], vdi[3], vsi[3];
    bool vld[3];
#pragma unroll
    for (int i = 0; i < 3; ++i) {
        int idx = t + i * 256;
        kro[i] = idx / 12; kso[i] = idx % 12;
        vld[i] = idx < 640; vdi[i] = idx >> 3; vsi[i] = idx & 7;
    }

    const bf16* kpb = kp + (size_t)bh * S_ * 96;
    const bf16* vpb = vt + (size_t)bh * 80 * S_;

    // prefetch tile 0 into regs
    uint4 krg[3], vrg[3];
#pragma unroll
    for (int i = 0; i < 3; ++i)
        krg[i] = *(const uint4*)(kpb + (size_t)kro[i] * 96 + kso[i] * 8);
#pragma unroll
    for (int i = 0; i < 3; ++i)
        if (vld[i]) vrg[i] = *(const uint4*)(vpb + (size_t)vdi[i] * S_ + vsi[i] * 8);

    float m_s = -1e30f, l_s = 0.f;
    v4f o_acc[5];
    v4f vzero = {0.f, 0.f, 0.f, 0.f};
#pragma unroll
    for (int nt = 0; nt < 5; ++nt) o_acc[nt] = vzero;

    for (int kb = 0; kb < S_ / 64; ++kb) {
        // commit staged regs -> LDS
#pragma unroll
        for (int i = 0; i < 3; ++i)
            *(uint4*)(&Ks[kro[i]][kso[i] * 8]) = krg[i];
#pragma unroll
        for (int i = 0; i < 3; ++i)
            if (vld[i]) *(uint4*)(&Vs[vdi[i]][vsi[i] * 8]) = vrg[i];
        __syncthreads();

        // issue next tile's global loads; latency hides under compute,
        // drained by the compiler's vmcnt(0) at the bottom barrier
        if (kb + 1 < S_ / 64) {
            const bf16* kn = kpb + (size_t)(kb + 1) * (64 * 96);
#pragma unroll
            for (int i = 0; i < 3; ++i)
                krg[i] = *(const uint4*)(kn + (size_t)kro[i] * 96 + kso[i] * 8);
#pragma unroll
            for (int i = 0; i < 3; ++i)
                if (vld[i]) vrg[i] = *(const uint4*)(vpb + (size_t)vdi[i] * S_ + (kb + 1) * 64 + vsi[i] * 8);
        }

        // S^T: sacc[kt][r] = S[q = w*16+lr][k = kt*16 + lq*4 + r]
        v4f sacc[4];
#pragma unroll
        for (int kt = 0; kt < 4; ++kt) sacc[kt] = vzero;
        __builtin_amdgcn_s_setprio(1);
#pragma unroll
        for (int ks = 0; ks < 3; ++ks)
#pragma unroll
            for (int kt = 0; kt < 4; ++kt) {
                v8bf kf = *(const v8bf*)(&Ks[kt * 16 + lr][ks * 32 + lq * 8]);
                sacc[kt] = mfma16(kf, qreg[ks], sacc[kt]);
            }
        __builtin_amdgcn_s_setprio(0);

        // online softmax: full row stats are lane-local (2 shuffles total)
        float mx = sacc[0][0];
#pragma unroll
        for (int kt = 0; kt < 4; ++kt)
#pragma unroll
            for (int r = 0; r < 4; ++r) mx = fmaxf(mx, sacc[kt][r]);
        mx = fmaxf(mx, __shfl_xor(mx, 16));
        mx = fmaxf(mx, __shfl_xor(mx, 32));
        float mnew = fmaxf(m_s, mx);
        float alpha = __builtin_amdgcn_exp2f(m_s - mnew);
        float ps = 0.f;
#pragma unroll
        for (int kt = 0; kt < 4; ++kt) {
            bf16 p4[4];
#pragma unroll
            for (int r = 0; r < 4; ++r) {
                float p = __builtin_amdgcn_exp2f(sacc[kt][r] - mnew);
                ps += p;
                p4[r] = (bf16)p;
            }
            // 4 consecutive k per lane -> packed 8B LDS store
            *(uint2*)(&Ps[lr * 72 + kt * 16 + lq * 4]) = *(const uint2*)p4;
        }
        ps += __shfl_xor(ps, 16);
        ps += __shfl_xor(ps, 32);
        l_s = l_s * alpha + ps;
        m_s = mnew;

        // rescale O (alpha is a lane scalar; overlaps with P ds_write latency)
#pragma unroll
        for (int nt = 0; nt < 5; ++nt)
#pragma unroll
            for (int r = 0; r < 4; ++r) o_acc[nt][r] *= alpha;

        asm volatile("s_waitcnt lgkmcnt(0)" ::: "memory");

        // PV with swapped operands: o_acc row=d(lq*4+r), col=q(lr) -> stats stay lane-local
        __builtin_amdgcn_s_setprio(1);
#pragma unroll
        for (int kt = 0; kt < 2; ++kt) {
            v8bf pf = *(const v8bf*)(&Ps[lr * 72 + kt * 32 + lq * 8]);
#pragma unroll
            for (int nt = 0; nt < 5; ++nt) {
                v8bf vf = *(const v8bf*)(&Vs[nt * 16 + lr][kt * 32 + lq * 8]);
                o_acc[nt] = mfma16(vf, pf, o_acc[nt]);
            }
        }
        __builtin_amdgcn_s_setprio(0);
        __syncthreads();
    }

    // epilogue: lane owns token q = w*16+lr, dims d = nt*16 + lq*4 + r
    float inv = 1.0f / l_s;
    bf16* obase = o + (size_t)(b * S_ + s0 + w * 16 + lr) * D_ + h * DH_;
#pragma unroll
    for (int nt = 0; nt < 4; ++nt)
#pragma unroll
        for (int r = 0; r < 4; ++r)
            obase[nt * 16 + lq * 4 + r] = (bf16)(o_acc[nt][r] * inv);
    if (lq == 0) obase[64] = (bf16)(o_acc[4][0] * inv);
}

// ---------------- final LayerNorm on z (f32) -> out f32 ----------------
__global__ __launch_bounds__(256) void k_ln_out(
    const float* __restrict__ z, const float* __restrict__ g,
    const float* __restrict__ bn, float* __restrict__ out)
{
    int row = blockIdx.x;
    int t = threadIdx.x;
    const float* zr = z + (size_t)row * E_;
    float4 v = *(const float4*)(zr + t * 4);
    float s = v.x + v.y + v.z + v.w;
    float ss = v.x * v.x + v.y * v.y + v.z * v.z + v.w * v.w;
#pragma unroll
    for (int off = 32; off; off >>= 1) {
        s  += __shfl_down(s, off);
        ss += __shfl_down(ss, off);
    }
    __shared__ float red[8];
    int wid = t >> 6;
    if ((t & 63) == 0) { red[wid] = s; red[4 + wid] = ss; }
    __syncthreads();
    float stot  = red[0] + red[1] + red[2] + red[3];
    float sstot = red[4] + red[5] + red[6] + red[7];
    float mean = stot * (1.0f / E_);
    float var  = sstot * (1.0f / E_) - mean * mean;
    float rs = rsqrtf(var + 1e-5f);
    float* outr = out + (size_t)row * E_;
    float vv[4] = {v.x, v.y, v.z, v.w};
#pragma unroll
    for (int j = 0; j < 4; ++j) {
        int i = t * 4 + j;
        outr[i] = ((vv[j] - mean) * rs) * g[i] + bn[i];
    }
}

// ---------------- launch ----------------
extern "C" void kernel_launch(void* const* d_in, const int* in_sizes, int n_in,
                              void* d_out, int out_size, void* d_ws, size_t ws_size,
                              hipStream_t stream) {
    const float* x    = (const float*)d_in[0];
    const float* cond = (const float*)d_in[1];
    const float* Wq   = (const float*)d_in[2];
    const float* bq   = (const float*)d_in[3];
    const float* Wv   = (const float*)d_in[4];
    const float* bv   = (const float*)d_in[5];
    const float* Wk   = (const float*)d_in[6];
    const float* bk   = (const float*)d_in[7];
    const float* Wo   = (const float*)d_in[8];
    const float* bo   = (const float*)d_in[9];
    const float* g1   = (const float*)d_in[10];
    const float* bn1  = (const float*)d_in[11];
    const float* g2   = (const float*)d_in[12];
    const float* bn2  = (const float*)d_in[13];
    const float* Wf1  = (const float*)d_in[14];
    const float* bf1  = (const float*)d_in[15];
    const float* Wf2  = (const float*)d_in[16];
    const float* bf2  = (const float*)d_in[17];
    float* out = (float*)d_out;

    char* ws = (char*)d_ws;
    bf16* Wqv_b = (bf16*)(ws + 0);            //  4,526,080
    bf16* Wo_b  = (bf16*)(ws + 4526080);      //  2,129,920 (1024 rows) -> 6,656,000
    bf16* Wf1_b = (bf16*)(ws + 6656000);      //  8,388,608 -> 15,044,608
    bf16* Wf2_b = (bf16*)(ws + 15044608);     //  8,388,608 -> 23,433,216
    bf16*  xc   = (bf16*)(ws + 23433216);     // 17,039,360 -> 40,472,576
    // K phase (dead after comb_k):
    bf16*  Bpk  = (bf16*)(ws + 40472576);     // 1152*8448*2 = 19,464,192 -> 59,936,768
    bf16*  Apk  = (bf16*)(ws + 59936768);     // 8192*4224*2 = 69,206,016 -> 129,142,784
    bf16*  P0k  = (bf16*)(ws + 129142784);    // 17,039,360 -> 146,182,144
    bf16*  P1k  = (bf16*)(ws + 146182144);    // 17,039,360 -> 163,221,504 (peak)
    // attention phase (aliases K-phase buffers):
    bf16*  qp   = (bf16*)(ws + 40472576);     // 25,165,824 -> 65,638,400
    bf16*  kp   = (bf16*)(ws + 65638400);     // 25,165,824 -> 90,804,224
    bf16*  vb   = (bf16*)(ws + 90804224);     // 17,039,360 -> 107,843,584 (hb post-attn)
    bf16*  hb   = (bf16*)(ws + 90804224);
    bf16*  vtb  = (bf16*)(ws + 107843584);    // 20,971,520 -> 128,815,104
    bf16*  ob   = (bf16*)(ws + 128815104);    // 17,039,360 -> 145,854,464
    // FF phase:
    bf16*  ff1  = (bf16*)(ws + 23433216);     // 67,108,864 -> 90,542,080 (< hb)
    float* zb   = (float*)(ws + 107843584);   // 33,554,432 -> 141,398,016

    k_cvt<<<(1081600 / 4 + 255) / 256, 256, 0, stream>>>(Wq, Wqv_b, 1081600);
    k_cvt<<<(1081600 / 4 + 255) / 256, 256, 0, stream>>>(Wv, Wqv_b + 1081600, 1081600);
    k_cvt<<<(1064960 / 4 + 255) / 256, 256, 0, stream>>>(Wo, Wo_b, 1064960);
    k_cvt<<<(4194304 / 4 + 255) / 256, 256, 0, stream>>>(Wf1, Wf1_b, 4194304);
    k_cvt<<<(4194304 / 4 + 255) / 256, 256, 0, stream>>>(Wf2, Wf2_b, 4194304);

    k_ln_concat<<<M_, 256, 0, stream>>>(x, cond, g1, bn1, xc);

    // K projection: B' repack, then two half-c passes over a shared A' buffer
    k_build_bk<<<dim3((1040 * 130 + 255) / 256, 8), 256, 0, stream>>>(Wk, Bpk);
    k_scale_a<<<(M_ * 132) / 256, 256, 0, stream>>>(xc, cond, 0, Apk);
    k_gemm_k2<<<576, 256, 0, stream>>>(Apk, Bpk, 0, P0k);
    k_scale_a<<<(M_ * 132) / 256, 256, 0, stream>>>(xc, cond, 4, Apk);
    k_gemm_k2<<<576, 256, 0, stream>>>(Apk, Bpk, KH_, P1k);

    k_zero_pads<<<4096, 256, 0, stream>>>(qp, kp);
    k_comb_k<<<(M_ * D_) / 256, 256, 0, stream>>>(P0k, P1k, cond, bk, kp);

    // fused Q+V (N=2080 over 17 n-blocks)
    k_gemm<EP_QV><<<64 * 17, 256, 0, stream>>>(xc, Wqv_b, bq, bv, M_, 2 * D_, D_, D_, D_, 17,
                                               qp, nullptr, 0, nullptr, 0, vb);

    k_transpose_v<<<dim3(S_ / 64, 64), 256, 0, stream>>>(vb, vtb);
    k_attn<<<dim3(S_ / 64, 64), 256, 0, stream>>>(qp, kp, vtb, ob);

    k_gemm<EP_O><<<64 * 8, 256, 0, stream>>>(ob, Wo_b, bo, nullptr, M_, E_, D_, D_, D_, 8,
                                             hb, nullptr, E_, xc, D_, nullptr);
    k_gemm<EP_FF1><<<64 * 32, 256, 0, stream>>>(hb, Wf1_b, bf1, nullptr, M_, DFF_, E_, E_, E_, 32,
                                                ff1, nullptr, DFF_, nullptr, 0, nullptr);
    k_gemm<EP_FF2><<<64 * 8, 256, 0, stream>>>(ff1, Wf2_b, bf2, nullptr, M_, E_, DFF_, DFF_, DFF_, 8,
                                               nullptr, zb, E_, hb, E_, nullptr);

    k_ln_out<<<M_, 256, 0, stream>>>(zb, g2, bn2, out);
}

// Round 2
// 1123.060 us; speedup vs baseline: 1.0759x; 1.0759x over previous
//
#include <hip/hip_runtime.h>
#include <hip/hip_bf16.h>
#include <math.h>

typedef __bf16 bf16;
typedef __bf16 v8bf __attribute__((ext_vector_type(8)));
typedef float v4f __attribute__((ext_vector_type(4)));

#define B_   4
#define S_   2048
#define E_   1024
#define CS_  16
#define NC_  8
#define H_   16
#define D_   1040
#define DH_  65
#define DFF_ 4096
#define M_   8192
#define KC_  1056          // padded per-c chunk
#define KH_  (4 * KC_)     // 4224, half-K
#define KB2_ (8 * KC_)     // 8448, B' row length

__device__ __forceinline__ v4f mfma16(v8bf a, v8bf b, v4f c) {
    return __builtin_amdgcn_mfma_f32_16x16x32_bf16(a, b, c, 0, 0, 0);
}

__device__ __forceinline__ void async16(const bf16* g, bf16* l) {
    __builtin_amdgcn_global_load_lds(
        (const __attribute__((address_space(1))) unsigned int*)g,
        (__attribute__((address_space(3))) unsigned int*)l, 16, 0, 0);
}

// ---------------- f32 -> bf16 weight conversion ----------------
__global__ __launch_bounds__(256) void k_cvt(const float* __restrict__ src,
                                             bf16* __restrict__ dst, int n) {
    int i = (blockIdx.x * 256 + threadIdx.x) * 4;
    if (i + 4 <= n) {
        float4 v = *(const float4*)(src + i);
        bf16 o[4] = {(bf16)v.x, (bf16)v.y, (bf16)v.z, (bf16)v.w};
        *(ushort4*)(dst + i) = *(const ushort4*)o;
    }
}

// ---------------- build B' for K-projection: Wk[c][n][j] -> B'[n][c*1056+j] ----------------
__global__ __launch_bounds__(256) void k_build_bk(const float* __restrict__ Wk,
                                                  bf16* __restrict__ Bp) {
    int c = blockIdx.y;
    int idx = blockIdx.x * 256 + threadIdx.x;     // 1040 * 130
    if (idx >= 1040 * 130) return;
    int n = idx / 130, u = idx - n * 130;
    const float* src = Wk + ((size_t)(c * D_ + n)) * D_ + u * 8;
    float4 a = *(const float4*)src;
    float4 b = *(const float4*)(src + 4);
    bf16 o[8] = {(bf16)a.x, (bf16)a.y, (bf16)a.z, (bf16)a.w,
                 (bf16)b.x, (bf16)b.y, (bf16)b.z, (bf16)b.w};
    *(uint4*)(Bp + (size_t)n * KB2_ + c * KC_ + u * 8) = *(const uint4*)o;
}

// ---------------- build half A': A'[m][cc*1056+j] = w[m,coff+cc]*xc[m][j] ----------------
__global__ __launch_bounds__(256) void k_scale_a(const bf16* __restrict__ xc,
                                                 const float* __restrict__ cond,
                                                 int coff, bf16* __restrict__ Ap) {
    int idx = blockIdx.x * 256 + threadIdx.x;     // 8192 * 132
    int m = idx / 132, u = idx - m * 132;
    int j = u * 8;
    float4 w4 = *(const float4*)(cond + (size_t)m * CS_ + coff);
    float wv[4] = {w4.x, w4.y, w4.z, w4.w};
    bf16* dst = Ap + (size_t)m * KH_ + j;
    if (j < D_) {
        union { uint4 u4; bf16 h[8]; } src;
        src.u4 = *(const uint4*)(xc + (size_t)m * D_ + j);
        float xv[8];
#pragma unroll
        for (int e = 0; e < 8; ++e) xv[e] = (float)src.h[e];
#pragma unroll
        for (int cc = 0; cc < 4; ++cc) {
            bf16 o[8];
#pragma unroll
            for (int e = 0; e < 8; ++e) o[e] = (bf16)(xv[e] * wv[cc]);
            *(uint4*)(dst + cc * KC_) = *(const uint4*)o;
        }
    } else {
        uint4 z = {0u, 0u, 0u, 0u};
#pragma unroll
        for (int cc = 0; cc < 4; ++cc) *(uint4*)(dst + cc * KC_) = z;
    }
}

// ---------------- zero qp/kp pad columns (d in [64,96) per row) ----------------
__global__ __launch_bounds__(256) void k_zero_pads(bf16* __restrict__ qp,
                                                   bf16* __restrict__ kp) {
    int i = blockIdx.x * 256 + threadIdx.x;     // 131072 rows * 8 uint4
    int row = i >> 3, j = i & 7;
    uint4 z = {0u, 0u, 0u, 0u};
    bf16* base = (j < 4) ? qp : kp;
    ((uint4*)(base + (size_t)row * 96 + 64))[j & 3] = z;
}

// ---------------- LayerNorm(x f32) + concat cond -> xc (M x D) bf16 ----------------
__global__ __launch_bounds__(256) void k_ln_concat(
    const float* __restrict__ x, const float* __restrict__ cond,
    const float* __restrict__ g, const float* __restrict__ bn,
    bf16* __restrict__ xc)
{
    int row = blockIdx.x;
    int t = threadIdx.x;
    const float* xr = x + (size_t)row * E_;
    float4 v = *(const float4*)(xr + t * 4);
    float s = v.x + v.y + v.z + v.w;
    float ss = v.x * v.x + v.y * v.y + v.z * v.z + v.w * v.w;
#pragma unroll
    for (int off = 32; off; off >>= 1) {
        s  += __shfl_down(s, off);
        ss += __shfl_down(ss, off);
    }
    __shared__ float red[8];
    int wid = t >> 6;
    if ((t & 63) == 0) { red[wid] = s; red[4 + wid] = ss; }
    __syncthreads();
    float stot  = red[0] + red[1] + red[2] + red[3];
    float sstot = red[4] + red[5] + red[6] + red[7];
    float mean = stot * (1.0f / E_);
    float var  = sstot * (1.0f / E_) - mean * mean;
    float rs = rsqrtf(var + 1e-5f);
    bf16* xcr = xc + (size_t)row * D_;
    float vv[4] = {v.x, v.y, v.z, v.w};
#pragma unroll
    for (int j = 0; j < 4; ++j) {
        int i = t * 4 + j;
        xcr[i] = (bf16)(((vv[j] - mean) * rs) * g[i] + bn[i]);
    }
    if (t < CS_) xcr[E_ + t] = (bf16)cond[(size_t)row * CS_ + t];
}

// ---------------- K-projection GEMM half: pure async16, K=4224, no remainder ----------------
__global__ __launch_bounds__(256) void k_gemm_k2(
    const bf16* __restrict__ A, const bf16* __restrict__ Bm,
    int koffB, bf16* __restrict__ Pout)
{
    __shared__ bf16 As[128][32];
    __shared__ bf16 Bs[128][32];
    int t = threadIdx.x;

    int pid = blockIdx.x;             // 576 = 8 gid * (8 mi * 9 ni)
    int gid = pid / 72;
    int rem = pid - gid * 72;
    int mi = gid * 8 + (rem & 7);
    int ni = rem >> 3;
    int m0 = mi << 7, n0 = ni << 7;

    int lane = t & 63, w = t >> 6;
    int wm = (w >> 1) * 64, wn = (w & 1) * 64;
    int lr = lane & 15, lq = lane >> 4;

    int row_i[2], seg_i[2];
#pragma unroll
    for (int i = 0; i < 2; ++i) { row_i[i] = (t + i * 256) >> 2; seg_i[i] = (t + i * 256) & 3; }

    v4f acc[4][4];
    v4f vzero = {0.f, 0.f, 0.f, 0.f};
#pragma unroll
    for (int mt = 0; mt < 4; ++mt)
#pragma unroll
        for (int nt = 0; nt < 4; ++nt) acc[mt][nt] = vzero;

    for (int kb = 0; kb < KH_ / 32; ++kb) {
        int k0 = kb << 5;
#pragma unroll
        for (int i = 0; i < 2; ++i) {
            async16(A + (size_t)(m0 + row_i[i]) * KH_ + k0 + seg_i[i] * 8,
                    &As[0][0] + (t + i * 256) * 8);
            async16(Bm + (size_t)(n0 + row_i[i]) * KB2_ + koffB + k0 + seg_i[i] * 8,
                    &Bs[0][0] + (t + i * 256) * 8);
        }
        __syncthreads();
        v8bf af[4], bfr[4];
#pragma unroll
        for (int mt = 0; mt < 4; ++mt) af[mt]  = *(const v8bf*)(&As[wm + mt * 16 + lr][lq * 8]);
#pragma unroll
        for (int nt = 0; nt < 4; ++nt) bfr[nt] = *(const v8bf*)(&Bs[wn + nt * 16 + lr][lq * 8]);
#pragma unroll
        for (int mt = 0; mt < 4; ++mt)
#pragma unroll
            for (int nt = 0; nt < 4; ++nt)
                acc[mt][nt] = mfma16(af[mt], bfr[nt], acc[mt][nt]);
        __syncthreads();
    }

#pragma unroll
    for (int mt = 0; mt < 4; ++mt)
#pragma unroll
        for (int reg = 0; reg < 4; ++reg) {
            int grow = m0 + wm + mt * 16 + lq * 4 + reg;
#pragma unroll
            for (int nt = 0; nt < 4; ++nt) {
                int gcol = n0 + wn + nt * 16 + lr;
                if (gcol < D_)
                    Pout[(size_t)grow * D_ + gcol] = (bf16)acc[mt][nt][reg];
            }
        }
}

// ---------------- combine K partials + cond*bk bias -> kp padded layout ----------------
__global__ __launch_bounds__(256) void k_comb_k(
    const bf16* __restrict__ P0, const bf16* __restrict__ P1,
    const float* __restrict__ condw, const float* __restrict__ bkp,
    bf16* __restrict__ kp)
{
    int idx = blockIdx.x * 256 + threadIdx.x;   // 8192*1040
    int m = idx / 1040, n = idx - m * 1040;
    float v = (float)P0[idx] + (float)P1[idx];
#pragma unroll
    for (int c = 0; c < NC_; ++c)
        v += condw[(size_t)m * CS_ + c] * bkp[(size_t)c * D_ + n];
    int h = n / 65, d = n - h * 65;
    int b = m >> 11, s = m & 2047;
    kp[(((size_t)(b * 16 + h)) * S_ + s) * 96 + d] = (bf16)v;
}

// ---------------- generic GEMM w/ epilogues (QV, O, FF1, FF2) ----------------
#define EP_QV  0
#define EP_O   1
#define EP_FF1 2
#define EP_FF2 3

template<int EP>
__global__ __launch_bounds__(256) void k_gemm(
    const bf16* __restrict__ A, const bf16* __restrict__ Bm,
    const float* __restrict__ bias, const float* __restrict__ bias2,
    int M, int N, int K, int lda, int ldb, int nbn,
    bf16* __restrict__ Cb, float* __restrict__ Cf, int ldc,
    const bf16* __restrict__ res, int ldres, bf16* __restrict__ Cb2)
{
    __shared__ bf16 As[128][32];
    __shared__ bf16 Bs[128][32];
    int t = threadIdx.x;

    int pid = blockIdx.x;
    int nig = 8 * nbn;
    int gid = pid / nig;
    int rem = pid - gid * nig;
    int mi = gid * 8 + (rem & 7);
    int ni = rem >> 3;
    int m0 = mi << 7, n0 = ni << 7;

    int lane = t & 63, w = t >> 6;
    int wm = (w >> 1) * 64, wn = (w & 1) * 64;
    int lr = lane & 15, lq = lane >> 4;

    int row_i[2], seg_i[2];
#pragma unroll
    for (int i = 0; i < 2; ++i) { row_i[i] = (t + i * 256) >> 2; seg_i[i] = (t + i * 256) & 3; }

    v4f acc[4][4];
    v4f vzero = {0.f, 0.f, 0.f, 0.f};
#pragma unroll
    for (int mt = 0; mt < 4; ++mt)
#pragma unroll
        for (int nt = 0; nt < 4; ++nt) acc[mt][nt] = vzero;

    const int KF = K >> 5;
    const bool KR = (K & 31) != 0;

    for (int kb = 0; kb < KF; ++kb) {
        int k0 = kb << 5;
#pragma unroll
        for (int i = 0; i < 2; ++i) {
            async16(A + (size_t)(m0 + row_i[i]) * lda + k0 + seg_i[i] * 8,
                    &As[0][0] + (t + i * 256) * 8);
            async16(Bm + (size_t)(n0 + row_i[i]) * ldb + k0 + seg_i[i] * 8,
                    &Bs[0][0] + (t + i * 256) * 8);
        }
        __syncthreads();
        v8bf af[4], bfr[4];
#pragma unroll
        for (int mt = 0; mt < 4; ++mt) af[mt]  = *(const v8bf*)(&As[wm + mt * 16 + lr][lq * 8]);
#pragma unroll
        for (int nt = 0; nt < 4; ++nt) bfr[nt] = *(const v8bf*)(&Bs[wn + nt * 16 + lr][lq * 8]);
#pragma unroll
        for (int mt = 0; mt < 4; ++mt)
#pragma unroll
            for (int nt = 0; nt < 4; ++nt)
                acc[mt][nt] = mfma16(af[mt], bfr[nt], acc[mt][nt]);
        __syncthreads();
    }
    if (KR) {
        int k0 = KF << 5;
#pragma unroll
        for (int i = 0; i < 2; ++i) {
            int gk = k0 + seg_i[i] * 8;
            uint4 val = {0u, 0u, 0u, 0u};
            if (gk + 8 <= K) val = *(const uint4*)(A + (size_t)(m0 + row_i[i]) * lda + gk);
            *(uint4*)(&As[row_i[i]][seg_i[i] * 8]) = val;
            uint4 bv = {0u, 0u, 0u, 0u};
            int gn = n0 + row_i[i];
            if (gn < N && gk + 8 <= K) bv = *(const uint4*)(Bm + (size_t)gn * ldb + gk);
            *(uint4*)(&Bs[row_i[i]][seg_i[i] * 8]) = bv;
        }
        __syncthreads();
        v8bf af[4], bfr[4];
#pragma unroll
        for (int mt = 0; mt < 4; ++mt) af[mt]  = *(const v8bf*)(&As[wm + mt * 16 + lr][lq * 8]);
#pragma unroll
        for (int nt = 0; nt < 4; ++nt) bfr[nt] = *(const v8bf*)(&Bs[wn + nt * 16 + lr][lq * 8]);
#pragma unroll
        for (int mt = 0; mt < 4; ++mt)
#pragma unroll
            for (int nt = 0; nt < 4; ++nt)
                acc[mt][nt] = mfma16(af[mt], bfr[nt], acc[mt][nt]);
        __syncthreads();
    }

#pragma unroll
    for (int mt = 0; mt < 4; ++mt) {
#pragma unroll
        for (int reg = 0; reg < 4; ++reg) {
            int grow = m0 + wm + mt * 16 + lq * 4 + reg;
#pragma unroll
            for (int nt = 0; nt < 4; ++nt) {
                int gcol = n0 + wn + nt * 16 + lr;
                float vacc = acc[mt][nt][reg];
                if constexpr (EP == EP_QV) {
                    if (gcol < D_) { // Q -> qp padded layout, pre-scaled by log2e/sqrt(65)
                        float o = (vacc + bias[gcol]) * 0.1789442960f;
                        int h = gcol / 65, d = gcol - h * 65;
                        int b = grow >> 11, s = grow & 2047;
                        Cb[(((size_t)(b * 16 + h)) * S_ + s) * 96 + d] = (bf16)o;
                    } else if (gcol < 2 * D_) { // V -> vb row-major
                        int col = gcol - D_;
                        Cb2[(size_t)grow * D_ + col] = (bf16)(vacc + bias2[col]);
                    }
                } else if constexpr (EP == EP_O) {
                    float o = vacc + bias[gcol] + (float)res[(size_t)grow * ldres + gcol];
                    Cb[(size_t)grow * ldc + gcol] = (bf16)o;
                } else if constexpr (EP == EP_FF1) {
                    float o = vacc + bias[gcol];
                    Cb[(size_t)grow * ldc + gcol] = (bf16)fmaxf(o, 0.f);
                } else { // EP_FF2 -> f32 z with bias + residual
                    Cf[(size_t)grow * ldc + gcol] =
                        vacc + bias[gcol] + (float)res[(size_t)grow * ldres + gcol];
                }
            }
        }
    }
}

// ---------------- transpose v (M x D bf16) into vt [bh][d(80)][s] ----------------
__global__ __launch_bounds__(256) void k_transpose_v(
    const bf16* __restrict__ v, bf16* __restrict__ vt)
{
    int bh = blockIdx.y, s0 = blockIdx.x * 64;
    int b = bh >> 4, h = bh & 15;
    __shared__ bf16 tile[80][65];
#pragma unroll
    for (int i = 0; i < 20; ++i) {
        int idx = threadIdx.x + i * 256;
        int d = idx % 80, sl = idx / 80;
        bf16 val = (bf16)0.f;
        if (d < DH_) val = v[((size_t)b * S_ + s0 + sl) * D_ + h * DH_ + d];
        tile[d][sl] = val;
    }
    __syncthreads();
#pragma unroll
    for (int i = 0; i < 20; ++i) {
        int idx = threadIdx.x + i * 256;
        int sl = idx % 64, d = idx / 64;
        vt[((size_t)bh * 80 + d) * S_ + s0 + sl] = tile[d][sl];
    }
}

// ---------------- flash attention (S^T softmax, LDS-dbuf K via async16, V direct) ----------------
__global__ __launch_bounds__(256) void k_attn(
    const bf16* __restrict__ qp, const bf16* __restrict__ kp,
    const bf16* __restrict__ vt, bf16* __restrict__ o)
{
    int bh = blockIdx.y;
    int s0 = blockIdx.x * 64;
    int b = bh >> 4, h = bh & 15;
    int t = threadIdx.x, lane = t & 63, w = t >> 6;
    int lr = lane & 15, lq = lane >> 4;

    // K double buffer: linear row-major [64][96] per tile (tile is contiguous in kp)
    __shared__ bf16 Kbuf[2][64 * 96];
    __shared__ bf16 Psh[4][16 * 72];
    bf16* Ps = Psh[w];
    bf16* k0p = &Kbuf[0][0];

    // Q fragments direct from global: row (w*16+lr), 16B-aligned chunks
    const bf16* qbase = qp + ((size_t)bh * S_ + s0 + w * 16 + lr) * 96;
    v8bf qreg[3];
#pragma unroll
    for (int ks = 0; ks < 3; ++ks)
        qreg[ks] = *(const v8bf*)(qbase + ks * 32 + lq * 8);

    const bf16* kpb = kp + (size_t)bh * S_ * 96;       // K tiles: kb*6144 contiguous
    const bf16* vbase = vt + ((size_t)bh * 80 + lr) * S_ + lq * 8;

    // stage tile 0 (coalesced: contiguous 12 KB, lane-linear LDS dest)
#pragma unroll
    for (int i = 0; i < 3; ++i)
        async16(kpb + (t + i * 256) * 8, k0p + (t + i * 256) * 8);

    float m_s = -1e30f, l_s = 0.f;
    v4f o_acc[5];
    v4f vzero = {0.f, 0.f, 0.f, 0.f};
#pragma unroll
    for (int nt = 0; nt < 5; ++nt) o_acc[nt] = vzero;

    __syncthreads();   // implicit vmcnt(0): K tile 0 resident

    int cur = 0;
    for (int kb = 0; kb < S_ / 64; ++kb) {
        const bf16* Kc = k0p + cur * (64 * 96);
        // prefetch next K tile into the other buffer (drained by bottom barrier)
        if (kb + 1 < S_ / 64) {
            bf16* Kn = k0p + (cur ^ 1) * (64 * 96);
            const bf16* src = kpb + (size_t)(kb + 1) * (64 * 96);
#pragma unroll
            for (int i = 0; i < 3; ++i)
                async16(src + (t + i * 256) * 8, Kn + (t + i * 256) * 8);
        }

        // S^T: sacc[kt][r] = S[k = kt*16 + lq*4 + r][q = w*16 + lr]
        v4f sacc[4];
#pragma unroll
        for (int kt = 0; kt < 4; ++kt) sacc[kt] = vzero;
        __builtin_amdgcn_s_setprio(1);
#pragma unroll
        for (int ks = 0; ks < 3; ++ks)
#pragma unroll
            for (int kt = 0; kt < 4; ++kt) {
                v8bf kf = *(const v8bf*)(Kc + (kt * 16 + lr) * 96 + ks * 32 + lq * 8);
                sacc[kt] = mfma16(kf, qreg[ks], sacc[kt]);
            }
        __builtin_amdgcn_s_setprio(0);

        // V fragments direct from global (L2-resident); softmax hides the latency
        v8bf vf0[5], vf1[5];
        const bf16* vb0 = vbase + kb * 64;
#pragma unroll
        for (int nt = 0; nt < 5; ++nt) vf0[nt] = *(const v8bf*)(vb0 + nt * 16 * S_);
#pragma unroll
        for (int nt = 0; nt < 5; ++nt) vf1[nt] = *(const v8bf*)(vb0 + nt * 16 * S_ + 32);

        // online softmax: full row stats lane-local (2 shuffles each)
        float mx = sacc[0][0];
#pragma unroll
        for (int kt = 0; kt < 4; ++kt)
#pragma unroll
            for (int r = 0; r < 4; ++r) mx = fmaxf(mx, sacc[kt][r]);
        mx = fmaxf(mx, __shfl_xor(mx, 16));
        mx = fmaxf(mx, __shfl_xor(mx, 32));
        float mnew = fmaxf(m_s, mx);
        float alpha = __builtin_amdgcn_exp2f(m_s - mnew);
        float ps = 0.f;
#pragma unroll
        for (int kt = 0; kt < 4; ++kt) {
            bf16 p4[4];
#pragma unroll
            for (int r = 0; r < 4; ++r) {
                float p = __builtin_amdgcn_exp2f(sacc[kt][r] - mnew);
                ps += p;
                p4[r] = (bf16)p;
            }
            *(uint2*)(&Ps[lr * 72 + kt * 16 + lq * 4]) = *(const uint2*)p4;
        }
        ps += __shfl_xor(ps, 16);
        ps += __shfl_xor(ps, 32);
        l_s = l_s * alpha + ps;
        m_s = mnew;

        // rescale O (lane-scalar alpha; overlaps with P ds_write latency)
#pragma unroll
        for (int nt = 0; nt < 5; ++nt)
#pragma unroll
            for (int r = 0; r < 4; ++r) o_acc[nt][r] *= alpha;

        asm volatile("s_waitcnt lgkmcnt(0)" ::: "memory");

        // PV: o_acc[nt][r] = O^T[d = nt*16 + lq*4 + r][q = w*16 + lr]
        __builtin_amdgcn_s_setprio(1);
        {
            v8bf pf0 = *(const v8bf*)(&Ps[lr * 72 + lq * 8]);
            v8bf pf1 = *(const v8bf*)(&Ps[lr * 72 + 32 + lq * 8]);
#pragma unroll
            for (int nt = 0; nt < 5; ++nt) o_acc[nt] = mfma16(vf0[nt], pf0, o_acc[nt]);
#pragma unroll
            for (int nt = 0; nt < 5; ++nt) o_acc[nt] = mfma16(vf1[nt], pf1, o_acc[nt]);
        }
        __builtin_amdgcn_s_setprio(0);
        __syncthreads();   // implicit vmcnt(0): next K tile resident; Kc free for reuse
        cur ^= 1;
    }

    // epilogue: lane owns token q = w*16+lr, dims d = nt*16 + lq*4 + r
    float inv = 1.0f / l_s;
    bf16* obase = o + (size_t)(b * S_ + s0 + w * 16 + lr) * D_ + h * DH_;
#pragma unroll
    for (int nt = 0; nt < 4; ++nt)
#pragma unroll
        for (int r = 0; r < 4; ++r)
            obase[nt * 16 + lq * 4 + r] = (bf16)(o_acc[nt][r] * inv);
    if (lq == 0) obase[64] = (bf16)(o_acc[4][0] * inv);
}

// ---------------- final LayerNorm on z (f32) -> out f32 ----------------
__global__ __launch_bounds__(256) void k_ln_out(
    const float* __restrict__ z, const float* __restrict__ g,
    const float* __restrict__ bn, float* __restrict__ out)
{
    int row = blockIdx.x;
    int t = threadIdx.x;
    const float* zr = z + (size_t)row * E_;
    float4 v = *(const float4*)(zr + t * 4);
    float s = v.x + v.y + v.z + v.w;
    float ss = v.x * v.x + v.y * v.y + v.z * v.z + v.w * v.w;
#pragma unroll
    for (int off = 32; off; off >>= 1) {
        s  += __shfl_down(s, off);
        ss += __shfl_down(ss, off);
    }
    __shared__ float red[8];
    int wid = t >> 6;
    if ((t & 63) == 0) { red[wid] = s; red[4 + wid] = ss; }
    __syncthreads();
    float stot  = red[0] + red[1] + red[2] + red[3];
    float sstot = red[4] + red[5] + red[6] + red[7];
    float mean = stot * (1.0f / E_);
    float var  = sstot * (1.0f / E_) - mean * mean;
    float rs = rsqrtf(var + 1e-5f);
    float* outr = out + (size_t)row * E_;
    float vv[4] = {v.x, v.y, v.z, v.w};
#pragma unroll
    for (int j = 0; j < 4; ++j) {
        int i = t * 4 + j;
        outr[i] = ((vv[j] - mean) * rs) * g[i] + bn[i];
    }
}

// ---------------- launch ----------------
extern "C" void kernel_launch(void* const* d_in, const int* in_sizes, int n_in,
                              void* d_out, int out_size, void* d_ws, size_t ws_size,
                              hipStream_t stream) {
    const float* x    = (const float*)d_in[0];
    const float* cond = (const float*)d_in[1];
    const float* Wq   = (const float*)d_in[2];
    const float* bq   = (const float*)d_in[3];
    const float* Wv   = (const float*)d_in[4];
    const float* bv   = (const float*)d_in[5];
    const float* Wk   = (const float*)d_in[6];
    const float* bk   = (const float*)d_in[7];
    const float* Wo   = (const float*)d_in[8];
    const float* bo   = (const float*)d_in[9];
    const float* g1   = (const float*)d_in[10];
    const float* bn1  = (const float*)d_in[11];
    const float* g2   = (const float*)d_in[12];
    const float* bn2  = (const float*)d_in[13];
    const float* Wf1  = (const float*)d_in[14];
    const float* bf1  = (const float*)d_in[15];
    const float* Wf2  = (const float*)d_in[16];
    const float* bf2  = (const float*)d_in[17];
    float* out = (float*)d_out;

    char* ws = (char*)d_ws;
    bf16* Wqv_b = (bf16*)(ws + 0);            //  4,526,080
    bf16* Wo_b  = (bf16*)(ws + 4526080);      //  2,129,920 (1024 rows) -> 6,656,000
    bf16* Wf1_b = (bf16*)(ws + 6656000);      //  8,388,608 -> 15,044,608
    bf16* Wf2_b = (bf16*)(ws + 15044608);     //  8,388,608 -> 23,433,216
    bf16*  xc   = (bf16*)(ws + 23433216);     // 17,039,360 -> 40,472,576
    // K phase (dead after comb_k):
    bf16*  Bpk  = (bf16*)(ws + 40472576);     // 1152*8448*2 = 19,464,192 -> 59,936,768
    bf16*  Apk  = (bf16*)(ws + 59936768);     // 8192*4224*2 = 69,206,016 -> 129,142,784
    bf16*  P0k  = (bf16*)(ws + 129142784);    // 17,039,360 -> 146,182,144
    bf16*  P1k  = (bf16*)(ws + 146182144);    // 17,039,360 -> 163,221,504 (peak)
    // attention phase (aliases K-phase buffers):
    bf16*  qp   = (bf16*)(ws + 40472576);     // 25,165,824 -> 65,638,400
    bf16*  kp   = (bf16*)(ws + 65638400);     // 25,165,824 -> 90,804,224
    bf16*  vb   = (bf16*)(ws + 90804224);     // 17,039,360 -> 107,843,584 (hb post-attn)
    bf16*  hb   = (bf16*)(ws + 90804224);
    bf16*  vtb  = (bf16*)(ws + 107843584);    // 20,971,520 -> 128,815,104
    bf16*  ob   = (bf16*)(ws + 128815104);    // 17,039,360 -> 145,854,464
    // FF phase:
    bf16*  ff1  = (bf16*)(ws + 23433216);     // 67,108,864 -> 90,542,080 (< hb)
    float* zb   = (float*)(ws + 107843584);   // 33,554,432 -> 141,398,016

    k_cvt<<<(1081600 / 4 + 255) / 256, 256, 0, stream>>>(Wq, Wqv_b, 1081600);
    k_cvt<<<(1081600 / 4 + 255) / 256, 256, 0, stream>>>(Wv, Wqv_b + 1081600, 1081600);
    k_cvt<<<(1064960 / 4 + 255) / 256, 256, 0, stream>>>(Wo, Wo_b, 1064960);
    k_cvt<<<(4194304 / 4 + 255) / 256, 256, 0, stream>>>(Wf1, Wf1_b, 4194304);
    k_cvt<<<(4194304 / 4 + 255) / 256, 256, 0, stream>>>(Wf2, Wf2_b, 4194304);

    k_ln_concat<<<M_, 256, 0, stream>>>(x, cond, g1, bn1, xc);

    // K projection: B' repack, then two half-c passes over a shared A' buffer
    k_build_bk<<<dim3((1040 * 130 + 255) / 256, 8), 256, 0, stream>>>(Wk, Bpk);
    k_scale_a<<<(M_ * 132) / 256, 256, 0, stream>>>(xc, cond, 0, Apk);
    k_gemm_k2<<<576, 256, 0, stream>>>(Apk, Bpk, 0, P0k);
    k_scale_a<<<(M_ * 132) / 256, 256, 0, stream>>>(xc, cond, 4, Apk);
    k_gemm_k2<<<576, 256, 0, stream>>>(Apk, Bpk, KH_, P1k);

    k_zero_pads<<<4096, 256, 0, stream>>>(qp, kp);
    k_comb_k<<<(M_ * D_) / 256, 256, 0, stream>>>(P0k, P1k, cond, bk, kp);

    // fused Q+V (N=2080 over 17 n-blocks)
    k_gemm<EP_QV><<<64 * 17, 256, 0, stream>>>(xc, Wqv_b, bq, bv, M_, 2 * D_, D_, D_, D_, 17,
                                               qp, nullptr, 0, nullptr, 0, vb);

    k_transpose_v<<<dim3(S_ / 64, 64), 256, 0, stream>>>(vb, vtb);
    k_attn<<<dim3(S_ / 64, 64), 256, 0, stream>>>(qp, kp, vtb, ob);

    k_gemm<EP_O><<<64 * 8, 256, 0, stream>>>(ob, Wo_b, bo, nullptr, M_, E_, D_, D_, D_, 8,
                                             hb, nullptr, E_, xc, D_, nullptr);
    k_gemm<EP_FF1><<<64 * 32, 256, 0, stream>>>(hb, Wf1_b, bf1, nullptr, M_, DFF_, E_, E_, E_, 32,
                                                ff1, nullptr, DFF_, nullptr, 0, nullptr);
    k_gemm<EP_FF2><<<64 * 8, 256, 0, stream>>>(ff1, Wf2_b, bf2, nullptr, M_, E_, DFF_, DFF_, DFF_, 8,
                                               nullptr, zb, E_, hb, E_, nullptr);

    k_ln_out<<<M_, 256, 0, stream>>>(zb, g2, bn2, out);
}

// Round 3
// 958.902 us; speedup vs baseline: 1.2601x; 1.1712x over previous
//
#include <hip/hip_runtime.h>
#include <hip/hip_bf16.h>
#include <math.h>

typedef __bf16 bf16;
typedef __bf16 v8bf __attribute__((ext_vector_type(8)));
typedef float v4f __attribute__((ext_vector_type(4)));

#define B_   4
#define S_   2048
#define E_   1024
#define CS_  16
#define NC_  8
#define H_   16
#define D_   1040
#define DH_  65
#define DFF_ 4096
#define M_   8192
#define KC_  1056          // padded per-c chunk
#define KH_  (4 * KC_)     // 4224, half-K
#define KB2_ (8 * KC_)     // 8448, B' row length

__device__ __forceinline__ v4f mfma16(v8bf a, v8bf b, v4f c) {
    return __builtin_amdgcn_mfma_f32_16x16x32_bf16(a, b, c, 0, 0, 0);
}

__device__ __forceinline__ void async16(const bf16* g, bf16* l) {
    __builtin_amdgcn_global_load_lds(
        (const __attribute__((address_space(1))) unsigned int*)g,
        (__attribute__((address_space(3))) unsigned int*)l, 16, 0, 0);
}

// ---------------- f32 -> bf16 weight conversion ----------------
__global__ __launch_bounds__(256) void k_cvt(const float* __restrict__ src,
                                             bf16* __restrict__ dst, int n) {
    int i = (blockIdx.x * 256 + threadIdx.x) * 4;
    if (i + 4 <= n) {
        float4 v = *(const float4*)(src + i);
        bf16 o[4] = {(bf16)v.x, (bf16)v.y, (bf16)v.z, (bf16)v.w};
        *(ushort4*)(dst + i) = *(const ushort4*)o;
    }
}

// ---------------- build B' for K-projection: Wk[c][n][j] -> B'[n][c*1056+j] ----------------
__global__ __launch_bounds__(256) void k_build_bk(const float* __restrict__ Wk,
                                                  bf16* __restrict__ Bp) {
    int c = blockIdx.y;
    int idx = blockIdx.x * 256 + threadIdx.x;     // 1040 * 130
    if (idx >= 1040 * 130) return;
    int n = idx / 130, u = idx - n * 130;
    const float* src = Wk + ((size_t)(c * D_ + n)) * D_ + u * 8;
    float4 a = *(const float4*)src;
    float4 b = *(const float4*)(src + 4);
    bf16 o[8] = {(bf16)a.x, (bf16)a.y, (bf16)a.z, (bf16)a.w,
                 (bf16)b.x, (bf16)b.y, (bf16)b.z, (bf16)b.w};
    *(uint4*)(Bp + (size_t)n * KB2_ + c * KC_ + u * 8) = *(const uint4*)o;
}

// ---------------- build half A': A'[m][cc*1056+j] = w[m,coff+cc]*xc[m][j] ----------------
__global__ __launch_bounds__(256) void k_scale_a(const bf16* __restrict__ xc,
                                                 const float* __restrict__ cond,
                                                 int coff, bf16* __restrict__ Ap) {
    int idx = blockIdx.x * 256 + threadIdx.x;     // 8192 * 132
    int m = idx / 132, u = idx - m * 132;
    int j = u * 8;
    float4 w4 = *(const float4*)(cond + (size_t)m * CS_ + coff);
    float wv[4] = {w4.x, w4.y, w4.z, w4.w};
    bf16* dst = Ap + (size_t)m * KH_ + j;
    if (j < D_) {
        union { uint4 u4; bf16 h[8]; } src;
        src.u4 = *(const uint4*)(xc + (size_t)m * D_ + j);
        float xv[8];
#pragma unroll
        for (int e = 0; e < 8; ++e) xv[e] = (float)src.h[e];
#pragma unroll
        for (int cc = 0; cc < 4; ++cc) {
            bf16 o[8];
#pragma unroll
            for (int e = 0; e < 8; ++e) o[e] = (bf16)(xv[e] * wv[cc]);
            *(uint4*)(dst + cc * KC_) = *(const uint4*)o;
        }
    } else {
        uint4 z = {0u, 0u, 0u, 0u};
#pragma unroll
        for (int cc = 0; cc < 4; ++cc) *(uint4*)(dst + cc * KC_) = z;
    }
}

// ---------------- zero qp/kp pad columns (d in [64,96) per row) ----------------
__global__ __launch_bounds__(256) void k_zero_pads(bf16* __restrict__ qp,
                                                   bf16* __restrict__ kp) {
    int i = blockIdx.x * 256 + threadIdx.x;     // 131072 rows * 8 uint4
    int row = i >> 3, j = i & 7;
    uint4 z = {0u, 0u, 0u, 0u};
    bf16* base = (j < 4) ? qp : kp;
    ((uint4*)(base + (size_t)row * 96 + 64))[j & 3] = z;
}

// ---------------- LayerNorm(x f32) + concat cond -> xc (M x D) bf16 ----------------
__global__ __launch_bounds__(256) void k_ln_concat(
    const float* __restrict__ x, const float* __restrict__ cond,
    const float* __restrict__ g, const float* __restrict__ bn,
    bf16* __restrict__ xc)
{
    int row = blockIdx.x;
    int t = threadIdx.x;
    const float* xr = x + (size_t)row * E_;
    float4 v = *(const float4*)(xr + t * 4);
    float s = v.x + v.y + v.z + v.w;
    float ss = v.x * v.x + v.y * v.y + v.z * v.z + v.w * v.w;
#pragma unroll
    for (int off = 32; off; off >>= 1) {
        s  += __shfl_down(s, off);
        ss += __shfl_down(ss, off);
    }
    __shared__ float red[8];
    int wid = t >> 6;
    if ((t & 63) == 0) { red[wid] = s; red[4 + wid] = ss; }
    __syncthreads();
    float stot  = red[0] + red[1] + red[2] + red[3];
    float sstot = red[4] + red[5] + red[6] + red[7];
    float mean = stot * (1.0f / E_);
    float var  = sstot * (1.0f / E_) - mean * mean;
    float rs = rsqrtf(var + 1e-5f);
    bf16* xcr = xc + (size_t)row * D_;
    float vv[4] = {v.x, v.y, v.z, v.w};
#pragma unroll
    for (int j = 0; j < 4; ++j) {
        int i = t * 4 + j;
        xcr[i] = (bf16)(((vv[j] - mean) * rs) * g[i] + bn[i]);
    }
    if (t < CS_) xcr[E_ + t] = (bf16)cond[(size_t)row * CS_ + t];
}

// ---------------- K-projection GEMM half: pure async16, K=4224, no remainder ----------------
__global__ __launch_bounds__(256) void k_gemm_k2(
    const bf16* __restrict__ A, const bf16* __restrict__ Bm,
    int koffB, bf16* __restrict__ Pout)
{
    __shared__ bf16 As[128][32];
    __shared__ bf16 Bs[128][32];
    int t = threadIdx.x;

    int pid = blockIdx.x;             // 576 = 8 gid * (8 mi * 9 ni)
    int gid = pid / 72;
    int rem = pid - gid * 72;
    int mi = gid * 8 + (rem & 7);
    int ni = rem >> 3;
    int m0 = mi << 7, n0 = ni << 7;

    int lane = t & 63, w = t >> 6;
    int wm = (w >> 1) * 64, wn = (w & 1) * 64;
    int lr = lane & 15, lq = lane >> 4;

    int row_i[2], seg_i[2];
#pragma unroll
    for (int i = 0; i < 2; ++i) { row_i[i] = (t + i * 256) >> 2; seg_i[i] = (t + i * 256) & 3; }

    v4f acc[4][4];
    v4f vzero = {0.f, 0.f, 0.f, 0.f};
#pragma unroll
    for (int mt = 0; mt < 4; ++mt)
#pragma unroll
        for (int nt = 0; nt < 4; ++nt) acc[mt][nt] = vzero;

    for (int kb = 0; kb < KH_ / 32; ++kb) {
        int k0 = kb << 5;
#pragma unroll
        for (int i = 0; i < 2; ++i) {
            async16(A + (size_t)(m0 + row_i[i]) * KH_ + k0 + seg_i[i] * 8,
                    &As[0][0] + (t + i * 256) * 8);
            async16(Bm + (size_t)(n0 + row_i[i]) * KB2_ + koffB + k0 + seg_i[i] * 8,
                    &Bs[0][0] + (t + i * 256) * 8);
        }
        __syncthreads();
        v8bf af[4], bfr[4];
#pragma unroll
        for (int mt = 0; mt < 4; ++mt) af[mt]  = *(const v8bf*)(&As[wm + mt * 16 + lr][lq * 8]);
#pragma unroll
        for (int nt = 0; nt < 4; ++nt) bfr[nt] = *(const v8bf*)(&Bs[wn + nt * 16 + lr][lq * 8]);
#pragma unroll
        for (int mt = 0; mt < 4; ++mt)
#pragma unroll
            for (int nt = 0; nt < 4; ++nt)
                acc[mt][nt] = mfma16(af[mt], bfr[nt], acc[mt][nt]);
        __syncthreads();
    }

#pragma unroll
    for (int mt = 0; mt < 4; ++mt)
#pragma unroll
        for (int reg = 0; reg < 4; ++reg) {
            int grow = m0 + wm + mt * 16 + lq * 4 + reg;
#pragma unroll
            for (int nt = 0; nt < 4; ++nt) {
                int gcol = n0 + wn + nt * 16 + lr;
                if (gcol < D_)
                    Pout[(size_t)grow * D_ + gcol] = (bf16)acc[mt][nt][reg];
            }
        }
}

// ---------------- combine K partials + cond*bk bias -> kp padded layout (pre-swizzled) ----------------
__global__ __launch_bounds__(256) void k_comb_k(
    const bf16* __restrict__ P0, const bf16* __restrict__ P1,
    const float* __restrict__ condw, const float* __restrict__ bkp,
    bf16* __restrict__ kp)
{
    int idx = blockIdx.x * 256 + threadIdx.x;   // 8192*1040
    int m = idx / 1040, n = idx - m * 1040;
    float v = (float)P0[idx] + (float)P1[idx];
#pragma unroll
    for (int c = 0; c < NC_; ++c)
        v += condw[(size_t)m * CS_ + c] * bkp[(size_t)c * D_ + n];
    int h = n / 65, d = n - h * 65;
    int b = m >> 11, s = m & 2047;
    // bank-conflict swizzle, matched by k_attn's LDS reads (XOR involution)
    int d2 = (d < 64) ? (d ^ ((s & 7) << 3)) : (d ^ ((s & 3) << 3));
    kp[(((size_t)(b * 16 + h)) * S_ + s) * 96 + d2] = (bf16)v;
}

// ---------------- generic GEMM w/ epilogues (QV, O, FF1, FF2) ----------------
#define EP_QV  0
#define EP_O   1
#define EP_FF1 2
#define EP_FF2 3

template<int EP>
__global__ __launch_bounds__(256) void k_gemm(
    const bf16* __restrict__ A, const bf16* __restrict__ Bm,
    const float* __restrict__ bias, const float* __restrict__ bias2,
    int M, int N, int K, int lda, int ldb, int nbn,
    bf16* __restrict__ Cb, float* __restrict__ Cf, int ldc,
    const bf16* __restrict__ res, int ldres, bf16* __restrict__ Cb2)
{
    __shared__ bf16 As[128][32];
    __shared__ bf16 Bs[128][32];
    int t = threadIdx.x;

    int pid = blockIdx.x;
    int nig = 8 * nbn;
    int gid = pid / nig;
    int rem = pid - gid * nig;
    int mi = gid * 8 + (rem & 7);
    int ni = rem >> 3;
    int m0 = mi << 7, n0 = ni << 7;

    int lane = t & 63, w = t >> 6;
    int wm = (w >> 1) * 64, wn = (w & 1) * 64;
    int lr = lane & 15, lq = lane >> 4;

    int row_i[2], seg_i[2];
#pragma unroll
    for (int i = 0; i < 2; ++i) { row_i[i] = (t + i * 256) >> 2; seg_i[i] = (t + i * 256) & 3; }

    v4f acc[4][4];
    v4f vzero = {0.f, 0.f, 0.f, 0.f};
#pragma unroll
    for (int mt = 0; mt < 4; ++mt)
#pragma unroll
        for (int nt = 0; nt < 4; ++nt) acc[mt][nt] = vzero;

    const int KF = K >> 5;
    const bool KR = (K & 31) != 0;

    for (int kb = 0; kb < KF; ++kb) {
        int k0 = kb << 5;
#pragma unroll
        for (int i = 0; i < 2; ++i) {
            async16(A + (size_t)(m0 + row_i[i]) * lda + k0 + seg_i[i] * 8,
                    &As[0][0] + (t + i * 256) * 8);
            async16(Bm + (size_t)(n0 + row_i[i]) * ldb + k0 + seg_i[i] * 8,
                    &Bs[0][0] + (t + i * 256) * 8);
        }
        __syncthreads();
        v8bf af[4], bfr[4];
#pragma unroll
        for (int mt = 0; mt < 4; ++mt) af[mt]  = *(const v8bf*)(&As[wm + mt * 16 + lr][lq * 8]);
#pragma unroll
        for (int nt = 0; nt < 4; ++nt) bfr[nt] = *(const v8bf*)(&Bs[wn + nt * 16 + lr][lq * 8]);
#pragma unroll
        for (int mt = 0; mt < 4; ++mt)
#pragma unroll
            for (int nt = 0; nt < 4; ++nt)
                acc[mt][nt] = mfma16(af[mt], bfr[nt], acc[mt][nt]);
        __syncthreads();
    }
    if (KR) {
        int k0 = KF << 5;
#pragma unroll
        for (int i = 0; i < 2; ++i) {
            int gk = k0 + seg_i[i] * 8;
            uint4 val = {0u, 0u, 0u, 0u};
            if (gk + 8 <= K) val = *(const uint4*)(A + (size_t)(m0 + row_i[i]) * lda + gk);
            *(uint4*)(&As[row_i[i]][seg_i[i] * 8]) = val;
            uint4 bv = {0u, 0u, 0u, 0u};
            int gn = n0 + row_i[i];
            if (gn < N && gk + 8 <= K) bv = *(const uint4*)(Bm + (size_t)gn * ldb + gk);
            *(uint4*)(&Bs[row_i[i]][seg_i[i] * 8]) = bv;
        }
        __syncthreads();
        v8bf af[4], bfr[4];
#pragma unroll
        for (int mt = 0; mt < 4; ++mt) af[mt]  = *(const v8bf*)(&As[wm + mt * 16 + lr][lq * 8]);
#pragma unroll
        for (int nt = 0; nt < 4; ++nt) bfr[nt] = *(const v8bf*)(&Bs[wn + nt * 16 + lr][lq * 8]);
#pragma unroll
        for (int mt = 0; mt < 4; ++mt)
#pragma unroll
            for (int nt = 0; nt < 4; ++nt)
                acc[mt][nt] = mfma16(af[mt], bfr[nt], acc[mt][nt]);
        __syncthreads();
    }

#pragma unroll
    for (int mt = 0; mt < 4; ++mt) {
#pragma unroll
        for (int reg = 0; reg < 4; ++reg) {
            int grow = m0 + wm + mt * 16 + lq * 4 + reg;
#pragma unroll
            for (int nt = 0; nt < 4; ++nt) {
                int gcol = n0 + wn + nt * 16 + lr;
                float vacc = acc[mt][nt][reg];
                if constexpr (EP == EP_QV) {
                    if (gcol < D_) { // Q -> qp padded layout, pre-scaled by log2e/sqrt(65)
                        float o = (vacc + bias[gcol]) * 0.1789442960f;
                        int h = gcol / 65, d = gcol - h * 65;
                        int b = grow >> 11, s = grow & 2047;
                        Cb[(((size_t)(b * 16 + h)) * S_ + s) * 96 + d] = (bf16)o;
                    } else if (gcol < 2 * D_) { // V -> vb row-major
                        int col = gcol - D_;
                        Cb2[(size_t)grow * D_ + col] = (bf16)(vacc + bias2[col]);
                    }
                } else if constexpr (EP == EP_O) {
                    float o = vacc + bias[gcol] + (float)res[(size_t)grow * ldres + gcol];
                    Cb[(size_t)grow * ldc + gcol] = (bf16)o;
                } else if constexpr (EP == EP_FF1) {
                    float o = vacc + bias[gcol];
                    Cb[(size_t)grow * ldc + gcol] = (bf16)fmaxf(o, 0.f);
                } else { // EP_FF2 -> f32 z with bias + residual
                    Cf[(size_t)grow * ldc + gcol] =
                        vacc + bias[gcol] + (float)res[(size_t)grow * ldres + gcol];
                }
            }
        }
    }
}

// ---------------- transpose v (M x D bf16) into vt [bh][d(80)][s] (pre-swizzled cols) ----------------
__global__ __launch_bounds__(256) void k_transpose_v(
    const bf16* __restrict__ v, bf16* __restrict__ vt)
{
    int bh = blockIdx.y, s0 = blockIdx.x * 64;
    int b = bh >> 4, h = bh & 15;
    __shared__ bf16 tile[80][65];
#pragma unroll
    for (int i = 0; i < 20; ++i) {
        int idx = threadIdx.x + i * 256;
        int d = idx % 80, sl = idx / 80;
        bf16 val = (bf16)0.f;
        if (d < DH_) val = v[((size_t)b * S_ + s0 + sl) * D_ + h * DH_ + d];
        tile[d][sl] = val;
    }
    __syncthreads();
#pragma unroll
    for (int i = 0; i < 20; ++i) {
        int idx = threadIdx.x + i * 256;
        int sl = idx % 64, d = idx / 64;
        int sl2 = sl ^ ((d & 7) << 3);   // bank-conflict swizzle within 64-col tile
        vt[((size_t)bh * 80 + d) * S_ + s0 + sl2] = tile[d][sl];
    }
}

// ---------------- flash attention (QBLK=128: 2 q-frags/wave; K+V async16 dbuf; S^T softmax) ----------------
__global__ __launch_bounds__(256) void k_attn(
    const bf16* __restrict__ qp, const bf16* __restrict__ kp,
    const bf16* __restrict__ vt, bf16* __restrict__ o)
{
    int bh = blockIdx.y;
    int s0 = blockIdx.x * 128;
    int b = bh >> 4, h = bh & 15;
    int t = threadIdx.x, lane = t & 63, w = t >> 6;
    int lr = lane & 15, lq = lane >> 4;

    __shared__ bf16 Kbuf[2][64 * 96];
    __shared__ bf16 Vbuf[2][80 * 64];
    __shared__ bf16 Psh[4][16 * 72];
    bf16* Ps = Psh[w];

    // Q fragments (two 64-row halves) direct from global
    v8bf qreg[2][3];
#pragma unroll
    for (int fq = 0; fq < 2; ++fq) {
        const bf16* qbase = qp + ((size_t)bh * S_ + s0 + fq * 64 + w * 16 + lr) * 96;
#pragma unroll
        for (int ks = 0; ks < 3; ++ks)
            qreg[fq][ks] = *(const v8bf*)(qbase + ks * 32 + lq * 8);
    }

    const bf16* kpb = kp + (size_t)bh * S_ * 96;
    const bf16* vpb = vt + (size_t)bh * 80 * S_;

    int vidx[3]; bool vact[3];
#pragma unroll
    for (int i = 0; i < 3; ++i) { vidx[i] = t + i * 256; vact[i] = vidx[i] < 640; }

    // prologue: stage tile 0 (K tile contiguous 12KB; V rows strided, per-lane src OK)
#pragma unroll
    for (int i = 0; i < 3; ++i)
        async16(kpb + (size_t)(t + i * 256) * 8, &Kbuf[0][(t + i * 256) * 8]);
#pragma unroll
    for (int i = 0; i < 3; ++i)
        if (vact[i])
            async16(vpb + (size_t)(vidx[i] >> 3) * S_ + (vidx[i] & 7) * 8, &Vbuf[0][vidx[i] * 8]);

    float m_0 = -1e30f, l_0 = 0.f, m_1 = -1e30f, l_1 = 0.f;
    v4f oa0[5], oa1[5];
    v4f vzero = {0.f, 0.f, 0.f, 0.f};
#pragma unroll
    for (int nt = 0; nt < 5; ++nt) { oa0[nt] = vzero; oa1[nt] = vzero; }

    int swA = (lr & 7) << 3;    // 3-bit swizzle (d<64 region / V)
    int swB = (lr & 3) << 3;    // 2-bit swizzle (K tail region d>=64)

    __syncthreads();   // implicit vmcnt(0): tile 0 resident

    int cur = 0;
    for (int kb = 0; kb < S_ / 64; ++kb) {
        if (kb + 1 < S_ / 64) {
            const bf16* ksrc = kpb + (size_t)(kb + 1) * (64 * 96);
            bf16* Kn = &Kbuf[cur ^ 1][0];
            bf16* Vn = &Vbuf[cur ^ 1][0];
#pragma unroll
            for (int i = 0; i < 3; ++i)
                async16(ksrc + (size_t)(t + i * 256) * 8, Kn + (t + i * 256) * 8);
#pragma unroll
            for (int i = 0; i < 3; ++i)
                if (vact[i])
                    async16(vpb + (size_t)(vidx[i] >> 3) * S_ + (kb + 1) * 64 + (vidx[i] & 7) * 8,
                            Vn + vidx[i] * 8);
        }
        const bf16* Kc = &Kbuf[cur][0];
        const bf16* Vc = &Vbuf[cur][0];

        // S^T for both q-frags; K fragments read once, feed both
        v4f s0acc[4], s1acc[4];
#pragma unroll
        for (int kt = 0; kt < 4; ++kt) { s0acc[kt] = vzero; s1acc[kt] = vzero; }
        __builtin_amdgcn_s_setprio(1);
#pragma unroll
        for (int ks = 0; ks < 3; ++ks) {
            int cb = (ks * 32 + lq * 8) ^ (ks == 2 ? swB : swA);
#pragma unroll
            for (int kt = 0; kt < 4; ++kt) {
                v8bf kf = *(const v8bf*)(Kc + (kt * 16 + lr) * 96 + cb);
                s0acc[kt] = mfma16(kf, qreg[0][ks], s0acc[kt]);
                s1acc[kt] = mfma16(kf, qreg[1][ks], s1acc[kt]);
            }
        }
        __builtin_amdgcn_s_setprio(0);

        // ---- online softmax frag0 -> Ps
        float a0;
        {
            float mx = s0acc[0][0];
#pragma unroll
            for (int kt = 0; kt < 4; ++kt)
#pragma unroll
                for (int r = 0; r < 4; ++r) mx = fmaxf(mx, s0acc[kt][r]);
            mx = fmaxf(mx, __shfl_xor(mx, 16));
            mx = fmaxf(mx, __shfl_xor(mx, 32));
            float mnew = fmaxf(m_0, mx);
            a0 = __builtin_amdgcn_exp2f(m_0 - mnew);
            float ps = 0.f;
#pragma unroll
            for (int kt = 0; kt < 4; ++kt) {
                union { bf16 h[4]; uint2 v; } p4;
#pragma unroll
                for (int r = 0; r < 4; ++r) {
                    float p = __builtin_amdgcn_exp2f(s0acc[kt][r] - mnew);
                    ps += p;
                    p4.h[r] = (bf16)p;
                }
                *(uint2*)(&Ps[lr * 72 + kt * 16 + lq * 4]) = p4.v;
            }
            ps += __shfl_xor(ps, 16);
            ps += __shfl_xor(ps, 32);
            l_0 = l_0 * a0 + ps;
            m_0 = mnew;
        }
        // ---- online softmax frag1 -> regs (Ps still holds P0)
        uint2 p1p[4];
        float a1;
        {
            float mx = s1acc[0][0];
#pragma unroll
            for (int kt = 0; kt < 4; ++kt)
#pragma unroll
                for (int r = 0; r < 4; ++r) mx = fmaxf(mx, s1acc[kt][r]);
            mx = fmaxf(mx, __shfl_xor(mx, 16));
            mx = fmaxf(mx, __shfl_xor(mx, 32));
            float mnew = fmaxf(m_1, mx);
            a1 = __builtin_amdgcn_exp2f(m_1 - mnew);
            float ps = 0.f;
#pragma unroll
            for (int kt = 0; kt < 4; ++kt) {
                union { bf16 h[4]; uint2 v; } p4;
#pragma unroll
                for (int r = 0; r < 4; ++r) {
                    float p = __builtin_amdgcn_exp2f(s1acc[kt][r] - mnew);
                    ps += p;
                    p4.h[r] = (bf16)p;
                }
                p1p[kt] = p4.v;
            }
            ps += __shfl_xor(ps, 16);
            ps += __shfl_xor(ps, 32);
            l_1 = l_1 * a1 + ps;
            m_1 = mnew;
        }

        // read P0 fragments, then overwrite Ps with P1, read P1 (same-wave DS order)
        v8bf pf0[2], pf1[2];
        pf0[0] = *(const v8bf*)(&Ps[lr * 72 + lq * 8]);
        pf0[1] = *(const v8bf*)(&Ps[lr * 72 + 32 + lq * 8]);
#pragma unroll
        for (int kt = 0; kt < 4; ++kt)
            *(uint2*)(&Ps[lr * 72 + kt * 16 + lq * 4]) = p1p[kt];
        pf1[0] = *(const v8bf*)(&Ps[lr * 72 + lq * 8]);
        pf1[1] = *(const v8bf*)(&Ps[lr * 72 + 32 + lq * 8]);

        // rescale accumulators (lane-scalar alphas)
#pragma unroll
        for (int nt = 0; nt < 5; ++nt)
#pragma unroll
            for (int r = 0; r < 4; ++r) { oa0[nt][r] *= a0; oa1[nt][r] *= a1; }

        // PV: V fragments read once, feed both frags
        __builtin_amdgcn_s_setprio(1);
#pragma unroll
        for (int kt2 = 0; kt2 < 2; ++kt2) {
            int vb2 = (kt2 * 32 + lq * 8) ^ swA;
#pragma unroll
            for (int nt = 0; nt < 5; ++nt) {
                v8bf vf = *(const v8bf*)(Vc + (nt * 16 + lr) * 64 + vb2);
                oa0[nt] = mfma16(vf, pf0[kt2], oa0[nt]);
                oa1[nt] = mfma16(vf, pf1[kt2], oa1[nt]);
            }
        }
        __builtin_amdgcn_s_setprio(0);
        __syncthreads();   // implicit vmcnt(0): next tiles resident
        cur ^= 1;
    }

    // epilogue: lane owns tokens q = s0 + fq*64 + w*16 + lr, dims d = nt*16 + lq*4 + r
#pragma unroll
    for (int fq = 0; fq < 2; ++fq) {
        float inv = 1.0f / (fq ? l_1 : l_0);
        const v4f* oa = fq ? oa1 : oa0;
        bf16* obase = o + (size_t)(b * S_ + s0 + fq * 64 + w * 16 + lr) * D_ + h * DH_;
#pragma unroll
        for (int nt = 0; nt < 4; ++nt)
#pragma unroll
            for (int r = 0; r < 4; ++r)
                obase[nt * 16 + lq * 4 + r] = (bf16)(oa[nt][r] * inv);
        if (lq == 0) obase[64] = (bf16)(oa[4][0] * inv);
    }
}

// ---------------- final LayerNorm on z (f32) -> out f32 ----------------
__global__ __launch_bounds__(256) void k_ln_out(
    const float* __restrict__ z, const float* __restrict__ g,
    const float* __restrict__ bn, float* __restrict__ out)
{
    int row = blockIdx.x;
    int t = threadIdx.x;
    const float* zr = z + (size_t)row * E_;
    float4 v = *(const float4*)(zr + t * 4);
    float s = v.x + v.y + v.z + v.w;
    float ss = v.x * v.x + v.y * v.y + v.z * v.z + v.w * v.w;
#pragma unroll
    for (int off = 32; off; off >>= 1) {
        s  += __shfl_down(s, off);
        ss += __shfl_down(ss, off);
    }
    __shared__ float red[8];
    int wid = t >> 6;
    if ((t & 63) == 0) { red[wid] = s; red[4 + wid] = ss; }
    __syncthreads();
    float stot  = red[0] + red[1] + red[2] + red[3];
    float sstot = red[4] + red[5] + red[6] + red[7];
    float mean = stot * (1.0f / E_);
    float var  = sstot * (1.0f / E_) - mean * mean;
    float rs = rsqrtf(var + 1e-5f);
    float* outr = out + (size_t)row * E_;
    float vv[4] = {v.x, v.y, v.z, v.w};
#pragma unroll
    for (int j = 0; j < 4; ++j) {
        int i = t * 4 + j;
        outr[i] = ((vv[j] - mean) * rs) * g[i] + bn[i];
    }
}

// ---------------- launch ----------------
extern "C" void kernel_launch(void* const* d_in, const int* in_sizes, int n_in,
                              void* d_out, int out_size, void* d_ws, size_t ws_size,
                              hipStream_t stream) {
    const float* x    = (const float*)d_in[0];
    const float* cond = (const float*)d_in[1];
    const float* Wq   = (const float*)d_in[2];
    const float* bq   = (const float*)d_in[3];
    const float* Wv   = (const float*)d_in[4];
    const float* bv   = (const float*)d_in[5];
    const float* Wk   = (const float*)d_in[6];
    const float* bk   = (const float*)d_in[7];
    const float* Wo   = (const float*)d_in[8];
    const float* bo   = (const float*)d_in[9];
    const float* g1   = (const float*)d_in[10];
    const float* bn1  = (const float*)d_in[11];
    const float* g2   = (const float*)d_in[12];
    const float* bn2  = (const float*)d_in[13];
    const float* Wf1  = (const float*)d_in[14];
    const float* bf1  = (const float*)d_in[15];
    const float* Wf2  = (const float*)d_in[16];
    const float* bf2  = (const float*)d_in[17];
    float* out = (float*)d_out;

    char* ws = (char*)d_ws;
    bf16* Wqv_b = (bf16*)(ws + 0);            //  4,526,080
    bf16* Wo_b  = (bf16*)(ws + 4526080);      //  2,129,920 (1024 rows) -> 6,656,000
    bf16* Wf1_b = (bf16*)(ws + 6656000);      //  8,388,608 -> 15,044,608
    bf16* Wf2_b = (bf16*)(ws + 15044608);     //  8,388,608 -> 23,433,216
    bf16*  xc   = (bf16*)(ws + 23433216);     // 17,039,360 -> 40,472,576
    // K phase (dead after comb_k):
    bf16*  Bpk  = (bf16*)(ws + 40472576);     // 1152*8448*2 = 19,464,192 -> 59,936,768
    bf16*  Apk  = (bf16*)(ws + 59936768);     // 8192*4224*2 = 69,206,016 -> 129,142,784
    bf16*  P0k  = (bf16*)(ws + 129142784);    // 17,039,360 -> 146,182,144
    bf16*  P1k  = (bf16*)(ws + 146182144);    // 17,039,360 -> 163,221,504 (peak)
    // attention phase (aliases K-phase buffers):
    bf16*  qp   = (bf16*)(ws + 40472576);     // 25,165,824 -> 65,638,400
    bf16*  kp   = (bf16*)(ws + 65638400);     // 25,165,824 -> 90,804,224
    bf16*  vb   = (bf16*)(ws + 90804224);     // 17,039,360 -> 107,843,584 (hb post-attn)
    bf16*  hb   = (bf16*)(ws + 90804224);
    bf16*  vtb  = (bf16*)(ws + 107843584);    // 20,971,520 -> 128,815,104
    bf16*  ob   = (bf16*)(ws + 128815104);    // 17,039,360 -> 145,854,464
    // FF phase:
    bf16*  ff1  = (bf16*)(ws + 23433216);     // 67,108,864 -> 90,542,080 (< hb)
    float* zb   = (float*)(ws + 107843584);   // 33,554,432 -> 141,398,016

    k_cvt<<<(1081600 / 4 + 255) / 256, 256, 0, stream>>>(Wq, Wqv_b, 1081600);
    k_cvt<<<(1081600 / 4 + 255) / 256, 256, 0, stream>>>(Wv, Wqv_b + 1081600, 1081600);
    k_cvt<<<(1064960 / 4 + 255) / 256, 256, 0, stream>>>(Wo, Wo_b, 1064960);
    k_cvt<<<(4194304 / 4 + 255) / 256, 256, 0, stream>>>(Wf1, Wf1_b, 4194304);
    k_cvt<<<(4194304 / 4 + 255) / 256, 256, 0, stream>>>(Wf2, Wf2_b, 4194304);

    k_ln_concat<<<M_, 256, 0, stream>>>(x, cond, g1, bn1, xc);

    // K projection: B' repack, then two half-c passes over a shared A' buffer
    k_build_bk<<<dim3((1040 * 130 + 255) / 256, 8), 256, 0, stream>>>(Wk, Bpk);
    k_scale_a<<<(M_ * 132) / 256, 256, 0, stream>>>(xc, cond, 0, Apk);
    k_gemm_k2<<<576, 256, 0, stream>>>(Apk, Bpk, 0, P0k);
    k_scale_a<<<(M_ * 132) / 256, 256, 0, stream>>>(xc, cond, 4, Apk);
    k_gemm_k2<<<576, 256, 0, stream>>>(Apk, Bpk, KH_, P1k);

    k_zero_pads<<<4096, 256, 0, stream>>>(qp, kp);
    k_comb_k<<<(M_ * D_) / 256, 256, 0, stream>>>(P0k, P1k, cond, bk, kp);

    // fused Q+V (N=2080 over 17 n-blocks)
    k_gemm<EP_QV><<<64 * 17, 256, 0, stream>>>(xc, Wqv_b, bq, bv, M_, 2 * D_, D_, D_, D_, 17,
                                               qp, nullptr, 0, nullptr, 0, vb);

    k_transpose_v<<<dim3(S_ / 64, 64), 256, 0, stream>>>(vb, vtb);
    k_attn<<<dim3(S_ / 128, 64), 256, 0, stream>>>(qp, kp, vtb, ob);

    k_gemm<EP_O><<<64 * 8, 256, 0, stream>>>(ob, Wo_b, bo, nullptr, M_, E_, D_, D_, D_, 8,
                                             hb, nullptr, E_, xc, D_, nullptr);
    k_gemm<EP_FF1><<<64 * 32, 256, 0, stream>>>(hb, Wf1_b, bf1, nullptr, M_, DFF_, E_, E_, E_, 32,
                                                ff1, nullptr, DFF_, nullptr, 0, nullptr);
    k_gemm<EP_FF2><<<64 * 8, 256, 0, stream>>>(ff1, Wf2_b, bf2, nullptr, M_, E_, DFF_, DFF_, DFF_, 8,
                                               nullptr, zb, E_, hb, E_, nullptr);

    k_ln_out<<<M_, 256, 0, stream>>>(zb, g2, bn2, out);
}

// Round 4
// 932.034 us; speedup vs baseline: 1.2964x; 1.0288x over previous
//
#include <hip/hip_runtime.h>
#include <hip/hip_bf16.h>
#include <math.h>

typedef __bf16 bf16;
typedef __bf16 v8bf __attribute__((ext_vector_type(8)));
typedef float v4f __attribute__((ext_vector_type(4)));

#define B_   4
#define S_   2048
#define E_   1024
#define CS_  16
#define NC_  8
#define H_   16
#define D_   1040
#define DH_  65
#define DFF_ 4096
#define M_   8192
#define KC_  1056          // padded per-c chunk
#define KH_  (4 * KC_)     // 4224, half-K
#define KB2_ (8 * KC_)     // 8448, B' row length

__device__ __forceinline__ v4f mfma16(v8bf a, v8bf b, v4f c) {
    return __builtin_amdgcn_mfma_f32_16x16x32_bf16(a, b, c, 0, 0, 0);
}

__device__ __forceinline__ void async16(const bf16* g, bf16* l) {
    __builtin_amdgcn_global_load_lds(
        (const __attribute__((address_space(1))) unsigned int*)g,
        (__attribute__((address_space(3))) unsigned int*)l, 16, 0, 0);
}

// XCD-aware bijective block swizzle (grid must be divisible by 8)
__device__ __forceinline__ int xcd_swz(int pid, int nwg) {
    int cpx = nwg >> 3;
    return (pid & 7) * cpx + (pid >> 3);
}

// ---------------- f32 -> bf16 weight conversion ----------------
__global__ __launch_bounds__(256) void k_cvt(const float* __restrict__ src,
                                             bf16* __restrict__ dst, int n) {
    int i = (blockIdx.x * 256 + threadIdx.x) * 4;
    if (i + 4 <= n) {
        float4 v = *(const float4*)(src + i);
        bf16 o[4] = {(bf16)v.x, (bf16)v.y, (bf16)v.z, (bf16)v.w};
        *(ushort4*)(dst + i) = *(const ushort4*)o;
    }
}

// ---------------- build B' for K-projection: Wk[c][n][j] -> B'[n][c*1056+j] ----------------
__global__ __launch_bounds__(256) void k_build_bk(const float* __restrict__ Wk,
                                                  bf16* __restrict__ Bp) {
    int c = blockIdx.y;
    int idx = blockIdx.x * 256 + threadIdx.x;     // 1040 * 130
    if (idx >= 1040 * 130) return;
    int n = idx / 130, u = idx - n * 130;
    const float* src = Wk + ((size_t)(c * D_ + n)) * D_ + u * 8;
    float4 a = *(const float4*)src;
    float4 b = *(const float4*)(src + 4);
    bf16 o[8] = {(bf16)a.x, (bf16)a.y, (bf16)a.z, (bf16)a.w,
                 (bf16)b.x, (bf16)b.y, (bf16)b.z, (bf16)b.w};
    *(uint4*)(Bp + (size_t)n * KB2_ + c * KC_ + u * 8) = *(const uint4*)o;
}

// ---------------- build half A': A'[m][cc*1056+j] = w[m,coff+cc]*xc[m][j] ----------------
__global__ __launch_bounds__(256) void k_scale_a(const bf16* __restrict__ xc,
                                                 const float* __restrict__ cond,
                                                 int coff, bf16* __restrict__ Ap) {
    int idx = blockIdx.x * 256 + threadIdx.x;     // 8192 * 132
    int m = idx / 132, u = idx - m * 132;
    int j = u * 8;
    float4 w4 = *(const float4*)(cond + (size_t)m * CS_ + coff);
    float wv[4] = {w4.x, w4.y, w4.z, w4.w};
    bf16* dst = Ap + (size_t)m * KH_ + j;
    if (j < D_) {
        union { uint4 u4; bf16 h[8]; } src;
        src.u4 = *(const uint4*)(xc + (size_t)m * D_ + j);
        float xv[8];
#pragma unroll
        for (int e = 0; e < 8; ++e) xv[e] = (float)src.h[e];
#pragma unroll
        for (int cc = 0; cc < 4; ++cc) {
            bf16 o[8];
#pragma unroll
            for (int e = 0; e < 8; ++e) o[e] = (bf16)(xv[e] * wv[cc]);
            *(uint4*)(dst + cc * KC_) = *(const uint4*)o;
        }
    } else {
        uint4 z = {0u, 0u, 0u, 0u};
#pragma unroll
        for (int cc = 0; cc < 4; ++cc) *(uint4*)(dst + cc * KC_) = z;
    }
}

// ---------------- zero qp/kp pad columns (d in [64,96) per row) ----------------
__global__ __launch_bounds__(256) void k_zero_pads(bf16* __restrict__ qp,
                                                   bf16* __restrict__ kp) {
    int i = blockIdx.x * 256 + threadIdx.x;     // 131072 rows * 8 uint4
    int row = i >> 3, j = i & 7;
    uint4 z = {0u, 0u, 0u, 0u};
    bf16* base = (j < 4) ? qp : kp;
    ((uint4*)(base + (size_t)row * 96 + 64))[j & 3] = z;
}

// ---------------- LayerNorm(x f32) + concat cond -> xc (M x D) bf16 ----------------
__global__ __launch_bounds__(256) void k_ln_concat(
    const float* __restrict__ x, const float* __restrict__ cond,
    const float* __restrict__ g, const float* __restrict__ bn,
    bf16* __restrict__ xc)
{
    int row = blockIdx.x;
    int t = threadIdx.x;
    const float* xr = x + (size_t)row * E_;
    float4 v = *(const float4*)(xr + t * 4);
    float s = v.x + v.y + v.z + v.w;
    float ss = v.x * v.x + v.y * v.y + v.z * v.z + v.w * v.w;
#pragma unroll
    for (int off = 32; off; off >>= 1) {
        s  += __shfl_down(s, off);
        ss += __shfl_down(ss, off);
    }
    __shared__ float red[8];
    int wid = t >> 6;
    if ((t & 63) == 0) { red[wid] = s; red[4 + wid] = ss; }
    __syncthreads();
    float stot  = red[0] + red[1] + red[2] + red[3];
    float sstot = red[4] + red[5] + red[6] + red[7];
    float mean = stot * (1.0f / E_);
    float var  = sstot * (1.0f / E_) - mean * mean;
    float rs = rsqrtf(var + 1e-5f);
    bf16* xcr = xc + (size_t)row * D_;
    float vv[4] = {v.x, v.y, v.z, v.w};
#pragma unroll
    for (int j = 0; j < 4; ++j) {
        int i = t * 4 + j;
        xcr[i] = (bf16)(((vv[j] - mean) * rs) * g[i] + bn[i]);
    }
    if (t < CS_) xcr[E_ + t] = (bf16)cond[(size_t)row * CS_ + t];
}

// ---------------- K-projection GEMM half: pure async16, K=4224, no remainder ----------------
__global__ __launch_bounds__(256) void k_gemm_k2(
    const bf16* __restrict__ A, const bf16* __restrict__ Bm,
    int koffB, bf16* __restrict__ Pout)
{
    __shared__ bf16 As[128][32];
    __shared__ bf16 Bs[128][32];
    int t = threadIdx.x;

    int pid = xcd_swz(blockIdx.x, gridDim.x); // 576 = 8 gid * (8 mi * 9 ni)
    int gid = pid / 72;
    int rem = pid - gid * 72;
    int mi = gid * 8 + (rem & 7);
    int ni = rem >> 3;
    int m0 = mi << 7, n0 = ni << 7;

    int lane = t & 63, w = t >> 6;
    int wm = (w >> 1) * 64, wn = (w & 1) * 64;
    int lr = lane & 15, lq = lane >> 4;

    int row_i[2], seg_i[2];
#pragma unroll
    for (int i = 0; i < 2; ++i) { row_i[i] = (t + i * 256) >> 2; seg_i[i] = (t + i * 256) & 3; }

    v4f acc[4][4];
    v4f vzero = {0.f, 0.f, 0.f, 0.f};
#pragma unroll
    for (int mt = 0; mt < 4; ++mt)
#pragma unroll
        for (int nt = 0; nt < 4; ++nt) acc[mt][nt] = vzero;

    for (int kb = 0; kb < KH_ / 32; ++kb) {
        int k0 = kb << 5;
#pragma unroll
        for (int i = 0; i < 2; ++i) {
            async16(A + (size_t)(m0 + row_i[i]) * KH_ + k0 + seg_i[i] * 8,
                    &As[0][0] + (t + i * 256) * 8);
            async16(Bm + (size_t)(n0 + row_i[i]) * KB2_ + koffB + k0 + seg_i[i] * 8,
                    &Bs[0][0] + (t + i * 256) * 8);
        }
        __syncthreads();
        v8bf af[4], bfr[4];
#pragma unroll
        for (int mt = 0; mt < 4; ++mt) af[mt]  = *(const v8bf*)(&As[wm + mt * 16 + lr][lq * 8]);
#pragma unroll
        for (int nt = 0; nt < 4; ++nt) bfr[nt] = *(const v8bf*)(&Bs[wn + nt * 16 + lr][lq * 8]);
#pragma unroll
        for (int mt = 0; mt < 4; ++mt)
#pragma unroll
            for (int nt = 0; nt < 4; ++nt)
                acc[mt][nt] = mfma16(af[mt], bfr[nt], acc[mt][nt]);
        __syncthreads();
    }

#pragma unroll
    for (int mt = 0; mt < 4; ++mt)
#pragma unroll
        for (int reg = 0; reg < 4; ++reg) {
            int grow = m0 + wm + mt * 16 + lq * 4 + reg;
#pragma unroll
            for (int nt = 0; nt < 4; ++nt) {
                int gcol = n0 + wn + nt * 16 + lr;
                if (gcol < D_)
                    Pout[(size_t)grow * D_ + gcol] = (bf16)acc[mt][nt][reg];
            }
        }
}

// ---------------- combine K partials + cond*bk bias -> kp padded layout (pre-swizzled) ----------------
__global__ __launch_bounds__(256) void k_comb_k(
    const bf16* __restrict__ P0, const bf16* __restrict__ P1,
    const float* __restrict__ condw, const float* __restrict__ bkp,
    bf16* __restrict__ kp)
{
    int idx = blockIdx.x * 256 + threadIdx.x;   // 8192*1040
    int m = idx / 1040, n = idx - m * 1040;
    float v = (float)P0[idx] + (float)P1[idx];
#pragma unroll
    for (int c = 0; c < NC_; ++c)
        v += condw[(size_t)m * CS_ + c] * bkp[(size_t)c * D_ + n];
    int h = n / 65, d = n - h * 65;
    int b = m >> 11, s = m & 2047;
    // bank-conflict swizzle, matched by k_attn's LDS reads (XOR involution)
    int d2 = (d < 64) ? (d ^ ((s & 7) << 3)) : (d ^ ((s & 3) << 3));
    kp[(((size_t)(b * 16 + h)) * S_ + s) * 96 + d2] = (bf16)v;
}

// ---------------- generic GEMM w/ epilogues (QV, O, FF1, FF2) ----------------
#define EP_QV  0
#define EP_O   1
#define EP_FF1 2
#define EP_FF2 3

template<int EP>
__global__ __launch_bounds__(256) void k_gemm(
    const bf16* __restrict__ A, const bf16* __restrict__ Bm,
    const float* __restrict__ bias, const float* __restrict__ bias2,
    int M, int N, int K, int lda, int ldb, int nbn,
    bf16* __restrict__ Cb, float* __restrict__ Cf, int ldc,
    const bf16* __restrict__ res, int ldres, bf16* __restrict__ Cb2)
{
    __shared__ bf16 As[128][32];
    __shared__ bf16 Bs[128][32];
    int t = threadIdx.x;

    int pid = xcd_swz(blockIdx.x, gridDim.x);
    int nig = 8 * nbn;
    int gid = pid / nig;
    int rem = pid - gid * nig;
    int mi = gid * 8 + (rem & 7);
    int ni = rem >> 3;
    int m0 = mi << 7, n0 = ni << 7;

    int lane = t & 63, w = t >> 6;
    int wm = (w >> 1) * 64, wn = (w & 1) * 64;
    int lr = lane & 15, lq = lane >> 4;

    int row_i[2], seg_i[2];
#pragma unroll
    for (int i = 0; i < 2; ++i) { row_i[i] = (t + i * 256) >> 2; seg_i[i] = (t + i * 256) & 3; }

    v4f acc[4][4];
    v4f vzero = {0.f, 0.f, 0.f, 0.f};
#pragma unroll
    for (int mt = 0; mt < 4; ++mt)
#pragma unroll
        for (int nt = 0; nt < 4; ++nt) acc[mt][nt] = vzero;

    const int KF = K >> 5;
    const bool KR = (K & 31) != 0;

    for (int kb = 0; kb < KF; ++kb) {
        int k0 = kb << 5;
#pragma unroll
        for (int i = 0; i < 2; ++i) {
            async16(A + (size_t)(m0 + row_i[i]) * lda + k0 + seg_i[i] * 8,
                    &As[0][0] + (t + i * 256) * 8);
            async16(Bm + (size_t)(n0 + row_i[i]) * ldb + k0 + seg_i[i] * 8,
                    &Bs[0][0] + (t + i * 256) * 8);
        }
        __syncthreads();
        v8bf af[4], bfr[4];
#pragma unroll
        for (int mt = 0; mt < 4; ++mt) af[mt]  = *(const v8bf*)(&As[wm + mt * 16 + lr][lq * 8]);
#pragma unroll
        for (int nt = 0; nt < 4; ++nt) bfr[nt] = *(const v8bf*)(&Bs[wn + nt * 16 + lr][lq * 8]);
#pragma unroll
        for (int mt = 0; mt < 4; ++mt)
#pragma unroll
            for (int nt = 0; nt < 4; ++nt)
                acc[mt][nt] = mfma16(af[mt], bfr[nt], acc[mt][nt]);
        __syncthreads();
    }
    if (KR) {
        int k0 = KF << 5;
#pragma unroll
        for (int i = 0; i < 2; ++i) {
            int gk = k0 + seg_i[i] * 8;
            uint4 val = {0u, 0u, 0u, 0u};
            if (gk + 8 <= K) val = *(const uint4*)(A + (size_t)(m0 + row_i[i]) * lda + gk);
            *(uint4*)(&As[row_i[i]][seg_i[i] * 8]) = val;
            uint4 bv = {0u, 0u, 0u, 0u};
            int gn = n0 + row_i[i];
            if (gn < N && gk + 8 <= K) bv = *(const uint4*)(Bm + (size_t)gn * ldb + gk);
            *(uint4*)(&Bs[row_i[i]][seg_i[i] * 8]) = bv;
        }
        __syncthreads();
        v8bf af[4], bfr[4];
#pragma unroll
        for (int mt = 0; mt < 4; ++mt) af[mt]  = *(const v8bf*)(&As[wm + mt * 16 + lr][lq * 8]);
#pragma unroll
        for (int nt = 0; nt < 4; ++nt) bfr[nt] = *(const v8bf*)(&Bs[wn + nt * 16 + lr][lq * 8]);
#pragma unroll
        for (int mt = 0; mt < 4; ++mt)
#pragma unroll
            for (int nt = 0; nt < 4; ++nt)
                acc[mt][nt] = mfma16(af[mt], bfr[nt], acc[mt][nt]);
        __syncthreads();
    }

#pragma unroll
    for (int mt = 0; mt < 4; ++mt) {
#pragma unroll
        for (int reg = 0; reg < 4; ++reg) {
            int grow = m0 + wm + mt * 16 + lq * 4 + reg;
#pragma unroll
            for (int nt = 0; nt < 4; ++nt) {
                int gcol = n0 + wn + nt * 16 + lr;
                float vacc = acc[mt][nt][reg];
                if constexpr (EP == EP_QV) {
                    if (gcol < D_) { // Q -> qp padded layout, pre-scaled by log2e/sqrt(65)
                        float o = (vacc + bias[gcol]) * 0.1789442960f;
                        int h = gcol / 65, d = gcol - h * 65;
                        int b = grow >> 11, s = grow & 2047;
                        Cb[(((size_t)(b * 16 + h)) * S_ + s) * 96 + d] = (bf16)o;
                    } else if (gcol < 2 * D_) { // V -> vb row-major
                        int col = gcol - D_;
                        Cb2[(size_t)grow * D_ + col] = (bf16)(vacc + bias2[col]);
                    }
                } else if constexpr (EP == EP_O) {
                    float o = vacc + bias[gcol] + (float)res[(size_t)grow * ldres + gcol];
                    Cb[(size_t)grow * ldc + gcol] = (bf16)o;
                } else if constexpr (EP == EP_FF1) {
                    float o = vacc + bias[gcol];
                    Cb[(size_t)grow * ldc + gcol] = (bf16)fmaxf(o, 0.f);
                } else { // EP_FF2 -> f32 z with bias + residual
                    Cf[(size_t)grow * ldc + gcol] =
                        vacc + bias[gcol] + (float)res[(size_t)grow * ldres + gcol];
                }
            }
        }
    }
}

// ---------------- transpose v into vt [bh][d(80)][s]; pad row 65 = ones (l-column) ----------------
__global__ __launch_bounds__(256) void k_transpose_v(
    const bf16* __restrict__ v, bf16* __restrict__ vt)
{
    int bh = blockIdx.y, s0 = blockIdx.x * 64;
    int b = bh >> 4, h = bh & 15;
    __shared__ bf16 tile[80][65];
#pragma unroll
    for (int i = 0; i < 20; ++i) {
        int idx = threadIdx.x + i * 256;
        int d = idx % 80, sl = idx / 80;
        bf16 val = (bf16)0.f;
        if (d < DH_) val = v[((size_t)b * S_ + s0 + sl) * D_ + h * DH_ + d];
        else if (d == DH_) val = (bf16)1.0f;   // ones row: PV accumulates sum(P) for free
        tile[d][sl] = val;
    }
    __syncthreads();
#pragma unroll
    for (int i = 0; i < 20; ++i) {
        int idx = threadIdx.x + i * 256;
        int sl = idx % 64, d = idx / 64;
        int sl2 = sl ^ ((d & 7) << 3);   // bank-conflict swizzle within 64-col tile
        vt[((size_t)bh * 80 + d) * S_ + s0 + sl2] = tile[d][sl];
    }
}

// ---------------- flash attention (QBLK=128, defer-max, MFMA l-column, XCD-grouped bh) ----------------
__global__ __launch_bounds__(256) void k_attn(
    const bf16* __restrict__ qp, const bf16* __restrict__ kp,
    const bf16* __restrict__ vt, bf16* __restrict__ o)
{
    // group bh onto XCDs: XCD g (= wgid%8) owns bh in [8g, 8g+8) -> ~5.8MB L2 working set
    int wgid = blockIdx.y * gridDim.x + blockIdx.x;   // gridDim.x = 16
    int g = wgid & 7, ii = wgid >> 3;
    int bh = g * 8 + (ii >> 4);
    int s0 = (ii & 15) * 128;
    int b = bh >> 4, h = bh & 15;
    int t = threadIdx.x, lane = t & 63, w = t >> 6;
    int lr = lane & 15, lq = lane >> 4;

    __shared__ bf16 Kbuf[2][64 * 96];
    __shared__ bf16 Vbuf[2][80 * 64];
    __shared__ bf16 Psh[4][16 * 72];
    bf16* Ps = Psh[w];

    // Q fragments (two 64-row halves) direct from global
    v8bf qreg[2][3];
#pragma unroll
    for (int fq = 0; fq < 2; ++fq) {
        const bf16* qbase = qp + ((size_t)bh * S_ + s0 + fq * 64 + w * 16 + lr) * 96;
#pragma unroll
        for (int ks = 0; ks < 3; ++ks)
            qreg[fq][ks] = *(const v8bf*)(qbase + ks * 32 + lq * 8);
    }

    const bf16* kpb = kp + (size_t)bh * S_ * 96;
    const bf16* vpb = vt + (size_t)bh * 80 * S_;

    int vidx[3]; bool vact[3];
#pragma unroll
    for (int i = 0; i < 3; ++i) { vidx[i] = t + i * 256; vact[i] = vidx[i] < 640; }

    // prologue: stage tile 0 (K tile contiguous 12KB; V rows strided, per-lane src OK)
#pragma unroll
    for (int i = 0; i < 3; ++i)
        async16(kpb + (size_t)(t + i * 256) * 8, &Kbuf[0][(t + i * 256) * 8]);
#pragma unroll
    for (int i = 0; i < 3; ++i)
        if (vact[i])
            async16(vpb + (size_t)(vidx[i] >> 3) * S_ + (vidx[i] & 7) * 8, &Vbuf[0][vidx[i] * 8]);

    float m_0 = -1e30f, m_1 = -1e30f;
    v4f oa0[5], oa1[5];
    v4f vzero = {0.f, 0.f, 0.f, 0.f};
#pragma unroll
    for (int nt = 0; nt < 5; ++nt) { oa0[nt] = vzero; oa1[nt] = vzero; }

    int swA = (lr & 7) << 3;    // 3-bit swizzle (d<64 region / V)
    int swB = (lr & 3) << 3;    // 2-bit swizzle (K tail region d>=64)

    __syncthreads();   // implicit vmcnt(0): tile 0 resident

    int cur = 0;
    for (int kb = 0; kb < S_ / 64; ++kb) {
        if (kb + 1 < S_ / 64) {
            const bf16* ksrc = kpb + (size_t)(kb + 1) * (64 * 96);
            bf16* Kn = &Kbuf[cur ^ 1][0];
            bf16* Vn = &Vbuf[cur ^ 1][0];
#pragma unroll
            for (int i = 0; i < 3; ++i)
                async16(ksrc + (size_t)(t + i * 256) * 8, Kn + (t + i * 256) * 8);
#pragma unroll
            for (int i = 0; i < 3; ++i)
                if (vact[i])
                    async16(vpb + (size_t)(vidx[i] >> 3) * S_ + (kb + 1) * 64 + (vidx[i] & 7) * 8,
                            Vn + vidx[i] * 8);
        }
        const bf16* Kc = &Kbuf[cur][0];
        const bf16* Vc = &Vbuf[cur][0];

        // S^T for both q-frags; K fragments read once, feed both
        v4f s0acc[4], s1acc[4];
#pragma unroll
        for (int kt = 0; kt < 4; ++kt) { s0acc[kt] = vzero; s1acc[kt] = vzero; }
        __builtin_amdgcn_s_setprio(1);
#pragma unroll
        for (int ks = 0; ks < 3; ++ks) {
            int cb = (ks * 32 + lq * 8) ^ (ks == 2 ? swB : swA);
#pragma unroll
            for (int kt = 0; kt < 4; ++kt) {
                v8bf kf = *(const v8bf*)(Kc + (kt * 16 + lr) * 96 + cb);
                s0acc[kt] = mfma16(kf, qreg[0][ks], s0acc[kt]);
                s1acc[kt] = mfma16(kf, qreg[1][ks], s1acc[kt]);
            }
        }
        __builtin_amdgcn_s_setprio(0);

        // ---- defer-max softmax frag0 -> Ps (sum comes free via V ones-row in PV)
        {
            float pmax = s0acc[0][0];
#pragma unroll
            for (int kt = 0; kt < 4; ++kt)
#pragma unroll
                for (int r = 0; r < 4; ++r) pmax = fmaxf(pmax, s0acc[kt][r]);
            if (!__all(pmax - m_0 <= 8.0f)) {   // rare: max grew -> reduce + rescale
                float mx = fmaxf(pmax, __shfl_xor(pmax, 16));
                mx = fmaxf(mx, __shfl_xor(mx, 32));
                float mnew = fmaxf(m_0, mx);
                float a0 = __builtin_amdgcn_exp2f(m_0 - mnew);
#pragma unroll
                for (int nt = 0; nt < 5; ++nt)
#pragma unroll
                    for (int r = 0; r < 4; ++r) oa0[nt][r] *= a0;   // rescales l-col too
                m_0 = mnew;
            }
#pragma unroll
            for (int kt = 0; kt < 4; ++kt) {
                union { bf16 h[4]; uint2 v; } p4;
#pragma unroll
                for (int r = 0; r < 4; ++r)
                    p4.h[r] = (bf16)__builtin_amdgcn_exp2f(s0acc[kt][r] - m_0);
                *(uint2*)(&Ps[lr * 72 + kt * 16 + lq * 4]) = p4.v;
            }
        }
        // ---- defer-max softmax frag1 -> regs (Ps still holds P0)
        uint2 p1p[4];
        {
            float pmax = s1acc[0][0];
#pragma unroll
            for (int kt = 0; kt < 4; ++kt)
#pragma unroll
                for (int r = 0; r < 4; ++r) pmax = fmaxf(pmax, s1acc[kt][r]);
            if (!__all(pmax - m_1 <= 8.0f)) {
                float mx = fmaxf(pmax, __shfl_xor(pmax, 16));
                mx = fmaxf(mx, __shfl_xor(mx, 32));
                float mnew = fmaxf(m_1, mx);
                float a1 = __builtin_amdgcn_exp2f(m_1 - mnew);
#pragma unroll
                for (int nt = 0; nt < 5; ++nt)
#pragma unroll
                    for (int r = 0; r < 4; ++r) oa1[nt][r] *= a1;
                m_1 = mnew;
            }
#pragma unroll
            for (int kt = 0; kt < 4; ++kt) {
                union { bf16 h[4]; uint2 v; } p4;
#pragma unroll
                for (int r = 0; r < 4; ++r)
                    p4.h[r] = (bf16)__builtin_amdgcn_exp2f(s1acc[kt][r] - m_1);
                p1p[kt] = p4.v;
            }
        }

        // read P0 fragments, then overwrite Ps with P1, read P1 (same-wave DS order)
        v8bf pf0[2], pf1[2];
        pf0[0] = *(const v8bf*)(&Ps[lr * 72 + lq * 8]);
        pf0[1] = *(const v8bf*)(&Ps[lr * 72 + 32 + lq * 8]);
#pragma unroll
        for (int kt = 0; kt < 4; ++kt)
            *(uint2*)(&Ps[lr * 72 + kt * 16 + lq * 4]) = p1p[kt];
        pf1[0] = *(const v8bf*)(&Ps[lr * 72 + lq * 8]);
        pf1[1] = *(const v8bf*)(&Ps[lr * 72 + 32 + lq * 8]);

        // PV: V fragments read once, feed both frags; nt=4 row 65 accumulates sum(P)
        __builtin_amdgcn_s_setprio(1);
#pragma unroll
        for (int kt2 = 0; kt2 < 2; ++kt2) {
            int vb2 = (kt2 * 32 + lq * 8) ^ swA;
#pragma unroll
            for (int nt = 0; nt < 5; ++nt) {
                v8bf vf = *(const v8bf*)(Vc + (nt * 16 + lr) * 64 + vb2);
                oa0[nt] = mfma16(vf, pf0[kt2], oa0[nt]);
                oa1[nt] = mfma16(vf, pf1[kt2], oa1[nt]);
            }
        }
        __builtin_amdgcn_s_setprio(0);
        __syncthreads();   // implicit vmcnt(0): next tiles resident
        cur ^= 1;
    }

    // l lives at d=65 -> oa[4][1] on lq==0 lanes; broadcast within lr-group
    float l0v = __shfl(oa0[4][1], lr);
    float l1v = __shfl(oa1[4][1], lr);

    // epilogue: lane owns tokens q = s0 + fq*64 + w*16 + lr, dims d = nt*16 + lq*4 + r
#pragma unroll
    for (int fq = 0; fq < 2; ++fq) {
        float inv = 1.0f / (fq ? l1v : l0v);
        const v4f* oa = fq ? oa1 : oa0;
        bf16* obase = o + (size_t)(b * S_ + s0 + fq * 64 + w * 16 + lr) * D_ + h * DH_;
#pragma unroll
        for (int nt = 0; nt < 4; ++nt)
#pragma unroll
            for (int r = 0; r < 4; ++r)
                obase[nt * 16 + lq * 4 + r] = (bf16)(oa[nt][r] * inv);
        if (lq == 0) obase[64] = (bf16)(oa[4][0] * inv);
    }
}

// ---------------- final LayerNorm on z (f32) -> out f32 ----------------
__global__ __launch_bounds__(256) void k_ln_out(
    const float* __restrict__ z, const float* __restrict__ g,
    const float* __restrict__ bn, float* __restrict__ out)
{
    int row = blockIdx.x;
    int t = threadIdx.x;
    const float* zr = z + (size_t)row * E_;
    float4 v = *(const float4*)(zr + t * 4);
    float s = v.x + v.y + v.z + v.w;
    float ss = v.x * v.x + v.y * v.y + v.z * v.z + v.w * v.w;
#pragma unroll
    for (int off = 32; off; off >>= 1) {
        s  += __shfl_down(s, off);
        ss += __shfl_down(ss, off);
    }
    __shared__ float red[8];
    int wid = t >> 6;
    if ((t & 63) == 0) { red[wid] = s; red[4 + wid] = ss; }
    __syncthreads();
    float stot  = red[0] + red[1] + red[2] + red[3];
    float sstot = red[4] + red[5] + red[6] + red[7];
    float mean = stot * (1.0f / E_);
    float var  = sstot * (1.0f / E_) - mean * mean;
    float rs = rsqrtf(var + 1e-5f);
    float* outr = out + (size_t)row * E_;
    float vv[4] = {v.x, v.y, v.z, v.w};
#pragma unroll
    for (int j = 0; j < 4; ++j) {
        int i = t * 4 + j;
        outr[i] = ((vv[j] - mean) * rs) * g[i] + bn[i];
    }
}

// ---------------- launch ----------------
extern "C" void kernel_launch(void* const* d_in, const int* in_sizes, int n_in,
                              void* d_out, int out_size, void* d_ws, size_t ws_size,
                              hipStream_t stream) {
    const float* x    = (const float*)d_in[0];
    const float* cond = (const float*)d_in[1];
    const float* Wq   = (const float*)d_in[2];
    const float* bq   = (const float*)d_in[3];
    const float* Wv   = (const float*)d_in[4];
    const float* bv   = (const float*)d_in[5];
    const float* Wk   = (const float*)d_in[6];
    const float* bk   = (const float*)d_in[7];
    const float* Wo   = (const float*)d_in[8];
    const float* bo   = (const float*)d_in[9];
    const float* g1   = (const float*)d_in[10];
    const float* bn1  = (const float*)d_in[11];
    const float* g2   = (const float*)d_in[12];
    const float* bn2  = (const float*)d_in[13];
    const float* Wf1  = (const float*)d_in[14];
    const float* bf1  = (const float*)d_in[15];
    const float* Wf2  = (const float*)d_in[16];
    const float* bf2  = (const float*)d_in[17];
    float* out = (float*)d_out;

    char* ws = (char*)d_ws;
    bf16* Wqv_b = (bf16*)(ws + 0);            //  4,526,080
    bf16* Wo_b  = (bf16*)(ws + 4526080);      //  2,129,920 (1024 rows) -> 6,656,000
    bf16* Wf1_b = (bf16*)(ws + 6656000);      //  8,388,608 -> 15,044,608
    bf16* Wf2_b = (bf16*)(ws + 15044608);     //  8,388,608 -> 23,433,216
    bf16*  xc   = (bf16*)(ws + 23433216);     // 17,039,360 -> 40,472,576
    // K phase (dead after comb_k):
    bf16*  Bpk  = (bf16*)(ws + 40472576);     // 1152*8448*2 = 19,464,192 -> 59,936,768
    bf16*  Apk  = (bf16*)(ws + 59936768);     // 8192*4224*2 = 69,206,016 -> 129,142,784
    bf16*  P0k  = (bf16*)(ws + 129142784);    // 17,039,360 -> 146,182,144
    bf16*  P1k  = (bf16*)(ws + 146182144);    // 17,039,360 -> 163,221,504 (peak)
    // attention phase (aliases K-phase buffers):
    bf16*  qp   = (bf16*)(ws + 40472576);     // 25,165,824 -> 65,638,400
    bf16*  kp   = (bf16*)(ws + 65638400);     // 25,165,824 -> 90,804,224
    bf16*  vb   = (bf16*)(ws + 90804224);     // 17,039,360 -> 107,843,584 (hb post-attn)
    bf16*  hb   = (bf16*)(ws + 90804224);
    bf16*  vtb  = (bf16*)(ws + 107843584);    // 20,971,520 -> 128,815,104
    bf16*  ob   = (bf16*)(ws + 128815104);    // 17,039,360 -> 145,854,464
    // FF phase:
    bf16*  ff1  = (bf16*)(ws + 23433216);     // 67,108,864 -> 90,542,080 (< hb)
    float* zb   = (float*)(ws + 107843584);   // 33,554,432 -> 141,398,016

    k_cvt<<<(1081600 / 4 + 255) / 256, 256, 0, stream>>>(Wq, Wqv_b, 1081600);
    k_cvt<<<(1081600 / 4 + 255) / 256, 256, 0, stream>>>(Wv, Wqv_b + 1081600, 1081600);
    k_cvt<<<(1064960 / 4 + 255) / 256, 256, 0, stream>>>(Wo, Wo_b, 1064960);
    k_cvt<<<(4194304 / 4 + 255) / 256, 256, 0, stream>>>(Wf1, Wf1_b, 4194304);
    k_cvt<<<(4194304 / 4 + 255) / 256, 256, 0, stream>>>(Wf2, Wf2_b, 4194304);

    k_ln_concat<<<M_, 256, 0, stream>>>(x, cond, g1, bn1, xc);

    // K projection: B' repack, then two half-c passes over a shared A' buffer
    k_build_bk<<<dim3((1040 * 130 + 255) / 256, 8), 256, 0, stream>>>(Wk, Bpk);
    k_scale_a<<<(M_ * 132) / 256, 256, 0, stream>>>(xc, cond, 0, Apk);
    k_gemm_k2<<<576, 256, 0, stream>>>(Apk, Bpk, 0, P0k);
    k_scale_a<<<(M_ * 132) / 256, 256, 0, stream>>>(xc, cond, 4, Apk);
    k_gemm_k2<<<576, 256, 0, stream>>>(Apk, Bpk, KH_, P1k);

    k_zero_pads<<<4096, 256, 0, stream>>>(qp, kp);
    k_comb_k<<<(M_ * D_) / 256, 256, 0, stream>>>(P0k, P1k, cond, bk, kp);

    // fused Q+V (N=2080 over 17 n-blocks)
    k_gemm<EP_QV><<<64 * 17, 256, 0, stream>>>(xc, Wqv_b, bq, bv, M_, 2 * D_, D_, D_, D_, 17,
                                               qp, nullptr, 0, nullptr, 0, vb);

    k_transpose_v<<<dim3(S_ / 64, 64), 256, 0, stream>>>(vb, vtb);
    k_attn<<<dim3(S_ / 128, 64), 256, 0, stream>>>(qp, kp, vtb, ob);

    k_gemm<EP_O><<<64 * 8, 256, 0, stream>>>(ob, Wo_b, bo, nullptr, M_, E_, D_, D_, D_, 8,
                                             hb, nullptr, E_, xc, D_, nullptr);
    k_gemm<EP_FF1><<<64 * 32, 256, 0, stream>>>(hb, Wf1_b, bf1, nullptr, M_, DFF_, E_, E_, E_, 32,
                                                ff1, nullptr, DFF_, nullptr, 0, nullptr);
    k_gemm<EP_FF2><<<64 * 8, 256, 0, stream>>>(ff1, Wf2_b, bf2, nullptr, M_, E_, DFF_, DFF_, DFF_, 8,
                                               nullptr, zb, E_, hb, E_, nullptr);

    k_ln_out<<<M_, 256, 0, stream>>>(zb, g2, bn2, out);
}